// Round 8
// baseline (1959.231 us; speedup 1.0000x reference)
//
#include <hip/hip_runtime.h>
#include <math.h>

#define NN 50000
#define TT 16
#define DD 128
#define MT (NN * TT)
#define SCAN_B 1024
#define SCAN_NB ((NN + SCAN_B - 1) / SCAN_B)  // 49

typedef __attribute__((ext_vector_type(8))) short short8;
typedef __attribute__((ext_vector_type(4))) float f32x4;
typedef __attribute__((ext_vector_type(4))) unsigned u32x4;

// ---------- bf16 helpers ----------
static __device__ __forceinline__ unsigned short f2bf(float f) {
  unsigned u = __float_as_uint(f);
  u += 0x7FFFu + ((u >> 16) & 1u);  // RNE
  return (unsigned short)(u >> 16);
}
static __device__ __forceinline__ float bf_lo(unsigned v) {
  return __uint_as_float(v << 16);
}
static __device__ __forceinline__ float bf_hi(unsigned v) {
  return __uint_as_float(v & 0xffff0000u);
}

// ---------- graph preprocessing ----------

__global__ void k_init(int* __restrict__ deg, int* __restrict__ cur) {
  int i = blockIdx.x * blockDim.x + threadIdx.x;
  if (i < NN) { deg[i] = 1; cur[i] = 0; }  // self loop; fill cursor
}

__global__ void k_deg_count(const int* __restrict__ dst, int* __restrict__ deg, int e) {
  int i = blockIdx.x * blockDim.x + threadIdx.x;
  if (i < e) atomicAdd(&deg[dst[i]], 1);
}

// scan over (deg-1) -> rowptr (block-local) + dinv fold
__global__ __launch_bounds__(SCAN_B) void k_scan1(const int* __restrict__ deg,
                                                  int* __restrict__ rowptr,
                                                  int* __restrict__ bsums,
                                                  float* __restrict__ dinv) {
  __shared__ int sm[SCAN_B];
  int tid = threadIdx.x;
  int i = blockIdx.x * SCAN_B + tid;
  int d = (i < NN) ? deg[i] : 1;
  if (i < NN) dinv[i] = rsqrtf((float)d);
  int v = d - 1;
  sm[tid] = v;
  __syncthreads();
  for (int off = 1; off < SCAN_B; off <<= 1) {
    int t = (tid >= off) ? sm[tid - off] : 0;
    __syncthreads();
    sm[tid] += t;
    __syncthreads();
  }
  if (i < NN) rowptr[i] = sm[tid] - v;
  if (tid == SCAN_B - 1) bsums[blockIdx.x] = sm[tid];
}

__global__ void k_scan2(int* __restrict__ bsums) {
  __shared__ int sm[64];
  int tid = threadIdx.x;
  int v = (tid < SCAN_NB) ? bsums[tid] : 0;
  sm[tid] = v;
  __syncthreads();
  for (int off = 1; off < 64; off <<= 1) {
    int t = (tid >= off) ? sm[tid - off] : 0;
    __syncthreads();
    sm[tid] += t;
    __syncthreads();
  }
  if (tid < SCAN_NB) bsums[tid] = sm[tid] - v;
  if (tid == 63) bsums[SCAN_NB] = sm[63];
}

__global__ __launch_bounds__(SCAN_B) void k_scan3(int* __restrict__ rowptr,
                                                  const int* __restrict__ bsums) {
  int i = blockIdx.x * SCAN_B + threadIdx.x;
  if (i < NN) rowptr[i] += bsums[blockIdx.x];
  if (i == 0) rowptr[NN] = bsums[SCAN_NB];
}

__global__ void k_fill(const int* __restrict__ src, const int* __restrict__ dst,
                       const int* __restrict__ rowptr, int* __restrict__ cur,
                       int* __restrict__ col, int e) {
  int i = blockIdx.x * blockDim.x + threadIdx.x;
  if (i < e) {
    int d = dst[i];
    int slot = atomicAdd(&cur[d], 1);
    col[rowptr[d] + slot] = src[i];
  }
}

// W^T bf16 + bsum fold: Wt[n*128+k] = bf16(W[k*128+n]); block = n, thread = k
__global__ void k_wprep(const float* __restrict__ Wc, const float* __restrict__ Wl,
                        const float* __restrict__ bc, const float* __restrict__ bl,
                        unsigned short* __restrict__ Wct, unsigned short* __restrict__ Wlt,
                        float* __restrict__ bsum) {
  int n = blockIdx.x, k = threadIdx.x;
  Wct[n * 128 + k] = f2bf(Wc[k * 128 + n]);
  Wlt[n * 128 + k] = f2bf(Wl[k * 128 + n]);
  if (n == 0) bsum[k] = bc[k] + bl[k];
}

// ---------- GEMM-X (MFMA bf16, swapped operands): Y[row] = bf16((X[row]@Wc)*dinv[row>>4]) ----------
__global__ __launch_bounds__(256) void k_gemmx(
    const float* __restrict__ X, const unsigned short* __restrict__ Wct,
    const float* __restrict__ dinv, unsigned* __restrict__ Yall)
{
  __shared__ unsigned short sA[128 * 136];  // sA[r][k], pad 136
  const int tid = threadIdx.x;
  const long row0 = (long)blockIdx.x * 128;

  // coalesced staging: wave reads 1KB contiguous per instruction
  {
    const float4* xp = (const float4*)(X + row0 * 128);
    #pragma unroll
    for (int it = 0; it < 16; ++it) {
      float4 v = xp[it * 256 + tid];
      int q = it * 256 + tid;          // float4 index in tile
      int r = q >> 5;                  // row
      int k = (q & 31) * 4;            // col
      unsigned u0 = (unsigned)f2bf(v.x) | ((unsigned)f2bf(v.y) << 16);
      unsigned u1 = (unsigned)f2bf(v.z) | ((unsigned)f2bf(v.w) << 16);
      *(uint2*)&sA[r * 136 + k] = make_uint2(u0, u1);
    }
  }
  __syncthreads();

  const int w = tid >> 6, l = tid & 63;
  const int lr = l & 15;
  const int lk = (l >> 4) << 3;
  f32x4 acc[2][8];
  #pragma unroll
  for (int i = 0; i < 2; ++i)
    #pragma unroll
    for (int n = 0; n < 8; ++n) acc[i][n] = (f32x4){0.f, 0.f, 0.f, 0.f};

  #pragma unroll
  for (int kg = 0; kg < 4; ++kg) {
    int kb = kg * 32 + lk;
    short8 a0 = *(const short8*)&sA[(w * 32 + lr) * 136 + kb];
    short8 a1 = *(const short8*)&sA[(w * 32 + 16 + lr) * 136 + kb];
    #pragma unroll
    for (int n = 0; n < 8; ++n) {
      short8 b = *(const short8*)&Wct[(n * 16 + lr) * 128 + kb];
      // swapped: lane holds xrow = l&15, wcol = (l>>4)*4+reg
      acc[0][n] = __builtin_amdgcn_mfma_f32_16x16x32_bf16(b, a0, acc[0][n], 0, 0, 0);
      acc[1][n] = __builtin_amdgcn_mfma_f32_16x16x32_bf16(b, a1, acc[1][n], 0, 0, 0);
    }
  }

  const int wb = (l >> 4) * 4;
  #pragma unroll
  for (int i = 0; i < 2; ++i) {
    long row = row0 + w * 32 + i * 16 + lr;
    float s = dinv[row >> 4];  // row = node*16+t
    #pragma unroll
    for (int n = 0; n < 8; ++n) {
      int c = n * 16 + wb;
      unsigned u0 = (unsigned)f2bf(acc[i][n][0] * s) | ((unsigned)f2bf(acc[i][n][1] * s) << 16);
      unsigned u1 = (unsigned)f2bf(acc[i][n][2] * s) | ((unsigned)f2bf(acc[i][n][3] * s) << 16);
      *(uint2*)(Yall + row * 64 + (c >> 1)) = make_uint2(u0, u1);
    }
  }
}

// ---------- gather: one block per node, all 16 t per edge (4KB coalesced row reads) ----------
// thread tid covers t = tid>>4, d = (tid&15)*8 .. +8  (one u32x4 = 8 bf16)
// t==0 lanes fuse step0. 8-deep edge unroll for MLP depth.
__global__ __launch_bounds__(256) void k_gatherN(
    const u32x4* __restrict__ Yall,  // [NN][256] u32x4
    const int* __restrict__ col, const int* __restrict__ rowptr,
    const float* __restrict__ dinv, const float* __restrict__ bsum,
    unsigned* __restrict__ aggbf, float* __restrict__ out, unsigned* __restrict__ h0)
{
  const int n = blockIdx.x;
  const int tid = threadIdx.x;
  float a0, a1, a2, a3, a4, a5, a6, a7;
  {
    u32x4 v = Yall[(long)n * 256 + tid];  // self loop
    a0 = bf_lo(v.x); a1 = bf_hi(v.x); a2 = bf_lo(v.y); a3 = bf_hi(v.y);
    a4 = bf_lo(v.z); a5 = bf_hi(v.z); a6 = bf_lo(v.w); a7 = bf_hi(v.w);
  }
  int j = rowptr[n];
  const int end = rowptr[n + 1];
  for (; j + 8 <= end; j += 8) {
    u32x4 v0 = Yall[(long)col[j]     * 256 + tid];
    u32x4 v1 = Yall[(long)col[j + 1] * 256 + tid];
    u32x4 v2 = Yall[(long)col[j + 2] * 256 + tid];
    u32x4 v3 = Yall[(long)col[j + 3] * 256 + tid];
    u32x4 v4 = Yall[(long)col[j + 4] * 256 + tid];
    u32x4 v5 = Yall[(long)col[j + 5] * 256 + tid];
    u32x4 v6 = Yall[(long)col[j + 6] * 256 + tid];
    u32x4 v7 = Yall[(long)col[j + 7] * 256 + tid];
    a0 += bf_lo(v0.x); a1 += bf_hi(v0.x); a2 += bf_lo(v0.y); a3 += bf_hi(v0.y);
    a4 += bf_lo(v0.z); a5 += bf_hi(v0.z); a6 += bf_lo(v0.w); a7 += bf_hi(v0.w);
    a0 += bf_lo(v1.x); a1 += bf_hi(v1.x); a2 += bf_lo(v1.y); a3 += bf_hi(v1.y);
    a4 += bf_lo(v1.z); a5 += bf_hi(v1.z); a6 += bf_lo(v1.w); a7 += bf_hi(v1.w);
    a0 += bf_lo(v2.x); a1 += bf_hi(v2.x); a2 += bf_lo(v2.y); a3 += bf_hi(v2.y);
    a4 += bf_lo(v2.z); a5 += bf_hi(v2.z); a6 += bf_lo(v2.w); a7 += bf_hi(v2.w);
    a0 += bf_lo(v3.x); a1 += bf_hi(v3.x); a2 += bf_lo(v3.y); a3 += bf_hi(v3.y);
    a4 += bf_lo(v3.z); a5 += bf_hi(v3.z); a6 += bf_lo(v3.w); a7 += bf_hi(v3.w);
    a0 += bf_lo(v4.x); a1 += bf_hi(v4.x); a2 += bf_lo(v4.y); a3 += bf_hi(v4.y);
    a4 += bf_lo(v4.z); a5 += bf_hi(v4.z); a6 += bf_lo(v4.w); a7 += bf_hi(v4.w);
    a0 += bf_lo(v5.x); a1 += bf_hi(v5.x); a2 += bf_lo(v5.y); a3 += bf_hi(v5.y);
    a4 += bf_lo(v5.z); a5 += bf_hi(v5.z); a6 += bf_lo(v5.w); a7 += bf_hi(v5.w);
    a0 += bf_lo(v6.x); a1 += bf_hi(v6.x); a2 += bf_lo(v6.y); a3 += bf_hi(v6.y);
    a4 += bf_lo(v6.z); a5 += bf_hi(v6.z); a6 += bf_lo(v6.w); a7 += bf_hi(v6.w);
    a0 += bf_lo(v7.x); a1 += bf_hi(v7.x); a2 += bf_lo(v7.y); a3 += bf_hi(v7.y);
    a4 += bf_lo(v7.z); a5 += bf_hi(v7.z); a6 += bf_lo(v7.w); a7 += bf_hi(v7.w);
  }
  for (; j < end; ++j) {
    u32x4 v = Yall[(long)col[j] * 256 + tid];
    a0 += bf_lo(v.x); a1 += bf_hi(v.x); a2 += bf_lo(v.y); a3 += bf_hi(v.y);
    a4 += bf_lo(v.z); a5 += bf_hi(v.z); a6 += bf_lo(v.w); a7 += bf_hi(v.w);
  }
  const float di = dinv[n];
  a0 *= di; a1 *= di; a2 *= di; a3 *= di;
  a4 *= di; a5 *= di; a6 *= di; a7 *= di;
  const int t = tid >> 4, dq = tid & 15;
  if (t == 0) {
    const float4 b0 = *(const float4*)&bsum[dq * 8];
    const float4 b1 = *(const float4*)&bsum[dq * 8 + 4];
    float o0 = tanhf(a0 + b0.x), o1 = tanhf(a1 + b0.y);
    float o2 = tanhf(a2 + b0.z), o3 = tanhf(a3 + b0.w);
    float o4 = tanhf(a4 + b1.x), o5 = tanhf(a5 + b1.y);
    float o6 = tanhf(a6 + b1.z), o7 = tanhf(a7 + b1.w);
    float* op = out + (long)n * (TT * DD) + dq * 8;
    *(float4*)op = make_float4(o0, o1, o2, o3);
    *(float4*)(op + 4) = make_float4(o4, o5, o6, o7);
    u32x4 h;
    h.x = (unsigned)f2bf(o0) | ((unsigned)f2bf(o1) << 16);
    h.y = (unsigned)f2bf(o2) | ((unsigned)f2bf(o3) << 16);
    h.z = (unsigned)f2bf(o4) | ((unsigned)f2bf(o5) << 16);
    h.w = (unsigned)f2bf(o6) | ((unsigned)f2bf(o7) << 16);
    *(u32x4*)(h0 + (long)n * 64 + dq * 4) = h;
  } else {
    u32x4 u;
    u.x = (unsigned)f2bf(a0) | ((unsigned)f2bf(a1) << 16);
    u.y = (unsigned)f2bf(a2) | ((unsigned)f2bf(a3) << 16);
    u.z = (unsigned)f2bf(a4) | ((unsigned)f2bf(a5) << 16);
    u.w = (unsigned)f2bf(a6) | ((unsigned)f2bf(a7) << 16);
    __builtin_nontemporal_store(u, (u32x4*)(aggbf + ((long)n * TT + t) * 64 + dq * 4));
  }
}

// ---------- recurrence GEMM (MFMA bf16, BM=64): out_t = tanh(h_{t-1}@Wl + agg_t + bsum) ----------
__global__ __launch_bounds__(256) void k_gemmh(
    const unsigned* __restrict__ hprev,      // [NN][64] uints (bf16 h_{t-1})
    const unsigned short* __restrict__ Wlt,  // [n][k] bf16 W_lin^T
    const unsigned* __restrict__ aggbf,
    const float* __restrict__ bsum,
    float* __restrict__ out, unsigned* __restrict__ hnew, int t)
{
  __shared__ unsigned short sA[64 * 136];
  const int tid = threadIdx.x;
  const int row0 = blockIdx.x * 64;

  {
    int r = tid >> 2, q = tid & 3;  // 4 threads per row
    int row = row0 + r;
    const uint4* sp = (const uint4*)(hprev + (long)row * 64 + q * 16);
    unsigned short* dp = &sA[r * 136 + q * 32];
    #pragma unroll
    for (int i = 0; i < 4; ++i) {
      uint4 v = make_uint4(0, 0, 0, 0);
      if (row < NN) v = sp[i];
      *(uint4*)(dp + i * 8) = v;
    }
  }
  __syncthreads();

  const int w = tid >> 6, l = tid & 63;
  const int lr = l & 15;
  const int lk = (l >> 4) << 3;
  f32x4 acc[8];
  #pragma unroll
  for (int n = 0; n < 8; ++n) acc[n] = (f32x4){0.f, 0.f, 0.f, 0.f};

  #pragma unroll
  for (int kg = 0; kg < 4; ++kg) {
    int kb = kg * 32 + lk;
    short8 a0 = *(const short8*)&sA[(w * 16 + lr) * 136 + kb];
    #pragma unroll
    for (int n = 0; n < 8; ++n) {
      short8 b = *(const short8*)&Wlt[(n * 16 + lr) * 128 + kb];
      acc[n] = __builtin_amdgcn_mfma_f32_16x16x32_bf16(b, a0, acc[n], 0, 0, 0);
    }
  }

  const int wb = (l >> 4) * 4;
  {
    int row = row0 + w * 16 + lr;
    if (row < NN) {
      #pragma unroll
      for (int n = 0; n < 8; ++n) {
        int c = n * 16 + wb;
        uint2 ag = *(const uint2*)(aggbf + ((long)row * TT + t) * 64 + (c >> 1));
        float4 bs = *(const float4*)&bsum[c];
        float o0 = tanhf(acc[n][0] + bf_lo(ag.x) + bs.x);
        float o1 = tanhf(acc[n][1] + bf_hi(ag.x) + bs.y);
        float o2 = tanhf(acc[n][2] + bf_lo(ag.y) + bs.z);
        float o3 = tanhf(acc[n][3] + bf_hi(ag.y) + bs.w);
        *(float4*)(out + ((long)row * TT + t) * 128 + c) = make_float4(o0, o1, o2, o3);
        unsigned u0 = (unsigned)f2bf(o0) | ((unsigned)f2bf(o1) << 16);
        unsigned u1 = (unsigned)f2bf(o2) | ((unsigned)f2bf(o3) << 16);
        *(uint2*)(hnew + (long)row * 64 + (c >> 1)) = make_uint2(u0, u1);
      }
    }
  }
}

extern "C" void kernel_launch(void* const* d_in, const int* in_sizes, int n_in,
                              void* d_out, int out_size, void* d_ws, size_t ws_size,
                              hipStream_t stream) {
  const float* x  = (const float*)d_in[0];
  const int*   ei = (const int*)d_in[1];
  const float* Wc = (const float*)d_in[2];
  const float* bc = (const float*)d_in[3];
  const float* Wl = (const float*)d_in[4];
  const float* bl = (const float*)d_in[5];
  float* out = (float*)d_out;
  const int E = in_sizes[1] / 2;
  const int* srcp = ei;
  const int* dstp = ei + E;

  char* w = (char*)d_ws;
  auto alloc = [&](size_t bytes) {
    char* p = w;
    w += (bytes + 255) & ~(size_t)255;
    return p;
  };
  int*            deg    = (int*)alloc(sizeof(int) * NN);
  float*          dinv   = (float*)alloc(sizeof(float) * NN);
  int*            rowptr = (int*)alloc(sizeof(int) * (NN + 1));
  int*            cur    = (int*)alloc(sizeof(int) * NN);
  int*            bsums  = (int*)alloc(sizeof(int) * (SCAN_NB + 1));
  int*            col    = (int*)alloc(sizeof(int) * (size_t)E);
  unsigned*       Yall   = (unsigned*)alloc(sizeof(unsigned) * (size_t)MT * 64);  // 204.8 MB
  unsigned*       aggbf  = (unsigned*)alloc(sizeof(unsigned) * (size_t)MT * 64);  // 204.8 MB
  unsigned*       hbf0   = (unsigned*)alloc(sizeof(unsigned) * (size_t)NN * 64);  // 12.8 MB
  unsigned*       hbf1   = (unsigned*)alloc(sizeof(unsigned) * (size_t)NN * 64);  // 12.8 MB
  float*          bsum   = (float*)alloc(sizeof(float) * DD);
  unsigned short* Wct    = (unsigned short*)alloc(sizeof(unsigned short) * 128 * 128);
  unsigned short* Wlt    = (unsigned short*)alloc(sizeof(unsigned short) * 128 * 128);

  k_init<<<(NN + 255) / 256, 256, 0, stream>>>(deg, cur);
  k_deg_count<<<(E + 255) / 256, 256, 0, stream>>>(dstp, deg, E);
  k_scan1<<<SCAN_NB, SCAN_B, 0, stream>>>(deg, rowptr, bsums, dinv);
  k_scan2<<<1, 64, 0, stream>>>(bsums);
  k_scan3<<<SCAN_NB, SCAN_B, 0, stream>>>(rowptr, bsums);
  k_fill<<<(E + 255) / 256, 256, 0, stream>>>(srcp, dstp, rowptr, cur, col, E);
  k_wprep<<<128, 128, 0, stream>>>(Wc, Wl, bc, bl, Wct, Wlt, bsum);

  // Y_all = bf16((x @ Wc) * dinv_src) for all N*T rows
  k_gemmx<<<MT / 128, 256, 0, stream>>>(x, Wct, dinv, Yall);
  // single-pass gather: block per node, 4KB coalesced row reads, step0 fused
  k_gatherN<<<NN, 256, 0, stream>>>((const u32x4*)Yall, col, rowptr, dinv, bsum,
                                    aggbf, out, hbf0);

  for (int t = 1; t < TT; ++t) {
    unsigned* hprev = (t & 1) ? hbf0 : hbf1;
    unsigned* hnew  = (t & 1) ? hbf1 : hbf0;
    k_gemmh<<<(NN + 63) / 64, 256, 0, stream>>>(hprev, Wlt, aggbf, bsum, out, hnew, t);
  }
}

// Round 9
// 1832.979 us; speedup vs baseline: 1.0689x; 1.0689x over previous
//
#include <hip/hip_runtime.h>
#include <math.h>

#define NN 50000
#define TT 16
#define DD 128
#define MT (NN * TT)
#define SCAN_B 1024
#define SCAN_NB ((NN + SCAN_B - 1) / SCAN_B)  // 49

typedef __attribute__((ext_vector_type(8))) short short8;
typedef __attribute__((ext_vector_type(4))) float f32x4;
typedef __attribute__((ext_vector_type(4))) unsigned u32x4;

// ---------- bf16 helpers ----------
static __device__ __forceinline__ unsigned short f2bf(float f) {
  unsigned u = __float_as_uint(f);
  u += 0x7FFFu + ((u >> 16) & 1u);  // RNE
  return (unsigned short)(u >> 16);
}
static __device__ __forceinline__ float bf_lo(unsigned v) {
  return __uint_as_float(v << 16);
}
static __device__ __forceinline__ float bf_hi(unsigned v) {
  return __uint_as_float(v & 0xffff0000u);
}

// ---------- graph preprocessing ----------

__global__ void k_init(int* __restrict__ deg, int* __restrict__ cur) {
  int i = blockIdx.x * blockDim.x + threadIdx.x;
  if (i < NN) { deg[i] = 1; cur[i] = 0; }  // self loop; fill cursor
}

__global__ void k_deg_count(const int* __restrict__ dst, int* __restrict__ deg, int e) {
  int i = blockIdx.x * blockDim.x + threadIdx.x;
  if (i < e) atomicAdd(&deg[dst[i]], 1);
}

// scan over (deg-1) -> rowptr (block-local) + dinv fold
__global__ __launch_bounds__(SCAN_B) void k_scan1(const int* __restrict__ deg,
                                                  int* __restrict__ rowptr,
                                                  int* __restrict__ bsums,
                                                  float* __restrict__ dinv) {
  __shared__ int sm[SCAN_B];
  int tid = threadIdx.x;
  int i = blockIdx.x * SCAN_B + tid;
  int d = (i < NN) ? deg[i] : 1;
  if (i < NN) dinv[i] = rsqrtf((float)d);
  int v = d - 1;
  sm[tid] = v;
  __syncthreads();
  for (int off = 1; off < SCAN_B; off <<= 1) {
    int t = (tid >= off) ? sm[tid - off] : 0;
    __syncthreads();
    sm[tid] += t;
    __syncthreads();
  }
  if (i < NN) rowptr[i] = sm[tid] - v;
  if (tid == SCAN_B - 1) bsums[blockIdx.x] = sm[tid];
}

__global__ void k_scan2(int* __restrict__ bsums) {
  __shared__ int sm[64];
  int tid = threadIdx.x;
  int v = (tid < SCAN_NB) ? bsums[tid] : 0;
  sm[tid] = v;
  __syncthreads();
  for (int off = 1; off < 64; off <<= 1) {
    int t = (tid >= off) ? sm[tid - off] : 0;
    __syncthreads();
    sm[tid] += t;
    __syncthreads();
  }
  if (tid < SCAN_NB) bsums[tid] = sm[tid] - v;
  if (tid == 63) bsums[SCAN_NB] = sm[63];
}

__global__ __launch_bounds__(SCAN_B) void k_scan3(int* __restrict__ rowptr,
                                                  const int* __restrict__ bsums) {
  int i = blockIdx.x * SCAN_B + threadIdx.x;
  if (i < NN) rowptr[i] += bsums[blockIdx.x];
  if (i == 0) rowptr[NN] = bsums[SCAN_NB];
}

__global__ void k_fill(const int* __restrict__ src, const int* __restrict__ dst,
                       const int* __restrict__ rowptr, int* __restrict__ cur,
                       int* __restrict__ col, int e) {
  int i = blockIdx.x * blockDim.x + threadIdx.x;
  if (i < e) {
    int d = dst[i];
    int slot = atomicAdd(&cur[d], 1);
    col[rowptr[d] + slot] = src[i];
  }
}

// W^T bf16 + bsum fold: Wt[n*128+k] = bf16(W[k*128+n]); block = n, thread = k
__global__ void k_wprep(const float* __restrict__ Wc, const float* __restrict__ Wl,
                        const float* __restrict__ bc, const float* __restrict__ bl,
                        unsigned short* __restrict__ Wct, unsigned short* __restrict__ Wlt,
                        float* __restrict__ bsum) {
  int n = blockIdx.x, k = threadIdx.x;
  Wct[n * 128 + k] = f2bf(Wc[k * 128 + n]);
  Wlt[n * 128 + k] = f2bf(Wl[k * 128 + n]);
  if (n == 0) bsum[k] = bc[k] + bl[k];
}

// ---------- GEMM-X (MFMA bf16, swapped operands): Y[row] = bf16((X[row]@Wc)*dinv[row>>4]) ----------
__global__ __launch_bounds__(256) void k_gemmx(
    const float* __restrict__ X, const unsigned short* __restrict__ Wct,
    const float* __restrict__ dinv, unsigned* __restrict__ Yall)
{
  __shared__ unsigned short sA[128 * 136];  // sA[r][k], pad 136
  const int tid = threadIdx.x;
  const long row0 = (long)blockIdx.x * 128;

  // coalesced staging: wave reads 1KB contiguous per instruction
  {
    const float4* xp = (const float4*)(X + row0 * 128);
    #pragma unroll
    for (int it = 0; it < 16; ++it) {
      float4 v = xp[it * 256 + tid];
      int q = it * 256 + tid;          // float4 index in tile
      int r = q >> 5;                  // row
      int k = (q & 31) * 4;            // col
      unsigned u0 = (unsigned)f2bf(v.x) | ((unsigned)f2bf(v.y) << 16);
      unsigned u1 = (unsigned)f2bf(v.z) | ((unsigned)f2bf(v.w) << 16);
      *(uint2*)&sA[r * 136 + k] = make_uint2(u0, u1);
    }
  }
  __syncthreads();

  const int w = tid >> 6, l = tid & 63;
  const int lr = l & 15;
  const int lk = (l >> 4) << 3;
  f32x4 acc[2][8];
  #pragma unroll
  for (int i = 0; i < 2; ++i)
    #pragma unroll
    for (int n = 0; n < 8; ++n) acc[i][n] = (f32x4){0.f, 0.f, 0.f, 0.f};

  #pragma unroll
  for (int kg = 0; kg < 4; ++kg) {
    int kb = kg * 32 + lk;
    short8 a0 = *(const short8*)&sA[(w * 32 + lr) * 136 + kb];
    short8 a1 = *(const short8*)&sA[(w * 32 + 16 + lr) * 136 + kb];
    #pragma unroll
    for (int n = 0; n < 8; ++n) {
      short8 b = *(const short8*)&Wct[(n * 16 + lr) * 128 + kb];
      // swapped: lane holds xrow = l&15, wcol = (l>>4)*4+reg
      acc[0][n] = __builtin_amdgcn_mfma_f32_16x16x32_bf16(b, a0, acc[0][n], 0, 0, 0);
      acc[1][n] = __builtin_amdgcn_mfma_f32_16x16x32_bf16(b, a1, acc[1][n], 0, 0, 0);
    }
  }

  const int wb = (l >> 4) * 4;
  #pragma unroll
  for (int i = 0; i < 2; ++i) {
    long row = row0 + w * 32 + i * 16 + lr;
    float s = dinv[row >> 4];  // row = node*16+t
    #pragma unroll
    for (int n = 0; n < 8; ++n) {
      int c = n * 16 + wb;
      unsigned u0 = (unsigned)f2bf(acc[i][n][0] * s) | ((unsigned)f2bf(acc[i][n][1] * s) << 16);
      unsigned u1 = (unsigned)f2bf(acc[i][n][2] * s) | ((unsigned)f2bf(acc[i][n][3] * s) << 16);
      *(uint2*)(Yall + row * 64 + (c >> 1)) = make_uint2(u0, u1);
    }
  }
}

// ---------- gather: one block per node, all 16 t per edge (4KB coalesced row reads) ----------
// thread tid covers t = tid>>4, d = (tid&15)*8 .. +8  (one u32x4 = 8 bf16)
// t==0 lanes fuse step0.
__global__ __launch_bounds__(256) void k_gatherN(
    const u32x4* __restrict__ Yall,  // [NN][256] u32x4
    const int* __restrict__ col, const int* __restrict__ rowptr,
    const float* __restrict__ dinv, const float* __restrict__ bsum,
    unsigned* __restrict__ aggbf, float* __restrict__ out, unsigned* __restrict__ h0)
{
  const int n = blockIdx.x;
  const int tid = threadIdx.x;
  float a0, a1, a2, a3, a4, a5, a6, a7;
  {
    u32x4 v = Yall[(long)n * 256 + tid];  // self loop
    a0 = bf_lo(v.x); a1 = bf_hi(v.x); a2 = bf_lo(v.y); a3 = bf_hi(v.y);
    a4 = bf_lo(v.z); a5 = bf_hi(v.z); a6 = bf_lo(v.w); a7 = bf_hi(v.w);
  }
  int j = rowptr[n];
  const int end = rowptr[n + 1];
  for (; j + 4 <= end; j += 4) {
    u32x4 v0 = Yall[(long)col[j]     * 256 + tid];
    u32x4 v1 = Yall[(long)col[j + 1] * 256 + tid];
    u32x4 v2 = Yall[(long)col[j + 2] * 256 + tid];
    u32x4 v3 = Yall[(long)col[j + 3] * 256 + tid];
    a0 += bf_lo(v0.x); a1 += bf_hi(v0.x); a2 += bf_lo(v0.y); a3 += bf_hi(v0.y);
    a4 += bf_lo(v0.z); a5 += bf_hi(v0.z); a6 += bf_lo(v0.w); a7 += bf_hi(v0.w);
    a0 += bf_lo(v1.x); a1 += bf_hi(v1.x); a2 += bf_lo(v1.y); a3 += bf_hi(v1.y);
    a4 += bf_lo(v1.z); a5 += bf_hi(v1.z); a6 += bf_lo(v1.w); a7 += bf_hi(v1.w);
    a0 += bf_lo(v2.x); a1 += bf_hi(v2.x); a2 += bf_lo(v2.y); a3 += bf_hi(v2.y);
    a4 += bf_lo(v2.z); a5 += bf_hi(v2.z); a6 += bf_lo(v2.w); a7 += bf_hi(v2.w);
    a0 += bf_lo(v3.x); a1 += bf_hi(v3.x); a2 += bf_lo(v3.y); a3 += bf_hi(v3.y);
    a4 += bf_lo(v3.z); a5 += bf_hi(v3.z); a6 += bf_lo(v3.w); a7 += bf_hi(v3.w);
  }
  for (; j < end; ++j) {
    u32x4 v = Yall[(long)col[j] * 256 + tid];
    a0 += bf_lo(v.x); a1 += bf_hi(v.x); a2 += bf_lo(v.y); a3 += bf_hi(v.y);
    a4 += bf_lo(v.z); a5 += bf_hi(v.z); a6 += bf_lo(v.w); a7 += bf_hi(v.w);
  }
  const float di = dinv[n];
  a0 *= di; a1 *= di; a2 *= di; a3 *= di;
  a4 *= di; a5 *= di; a6 *= di; a7 *= di;
  const int t = tid >> 4, dq = tid & 15;
  if (t == 0) {
    const float4 b0 = *(const float4*)&bsum[dq * 8];
    const float4 b1 = *(const float4*)&bsum[dq * 8 + 4];
    float o0 = tanhf(a0 + b0.x), o1 = tanhf(a1 + b0.y);
    float o2 = tanhf(a2 + b0.z), o3 = tanhf(a3 + b0.w);
    float o4 = tanhf(a4 + b1.x), o5 = tanhf(a5 + b1.y);
    float o6 = tanhf(a6 + b1.z), o7 = tanhf(a7 + b1.w);
    float* op = out + (long)n * (TT * DD) + dq * 8;
    *(float4*)op = make_float4(o0, o1, o2, o3);
    *(float4*)(op + 4) = make_float4(o4, o5, o6, o7);
    u32x4 h;
    h.x = (unsigned)f2bf(o0) | ((unsigned)f2bf(o1) << 16);
    h.y = (unsigned)f2bf(o2) | ((unsigned)f2bf(o3) << 16);
    h.z = (unsigned)f2bf(o4) | ((unsigned)f2bf(o5) << 16);
    h.w = (unsigned)f2bf(o6) | ((unsigned)f2bf(o7) << 16);
    *(u32x4*)(h0 + (long)n * 64 + dq * 4) = h;
  } else {
    u32x4 u;
    u.x = (unsigned)f2bf(a0) | ((unsigned)f2bf(a1) << 16);
    u.y = (unsigned)f2bf(a2) | ((unsigned)f2bf(a3) << 16);
    u.z = (unsigned)f2bf(a4) | ((unsigned)f2bf(a5) << 16);
    u.w = (unsigned)f2bf(a6) | ((unsigned)f2bf(a7) << 16);
    __builtin_nontemporal_store(u, (u32x4*)(aggbf + ((long)n * TT + t) * 64 + dq * 4));
  }
}

// ---------- recurrence GEMM (MFMA bf16, wave-autonomous, no LDS) ----------
// Each wave: 16 rows x 64 cols. A-fragments loaded directly from global
// (lane (lr,lg): 16B at hprev[row=task*16+lr][kg*32+lg*8] — 4 lanes/64B line).
// 6250 waves -> ~6 waves/SIMD for latency hiding; no __syncthreads.
__global__ __launch_bounds__(256) void k_gemmh(
    const unsigned short* __restrict__ hprev,  // [NN][128] bf16
    const unsigned short* __restrict__ Wlt,    // [n][k] bf16 W_lin^T
    const unsigned* __restrict__ aggbf,
    const float* __restrict__ bsum,
    float* __restrict__ out, unsigned* __restrict__ hnew, int t)
{
  const int wid = blockIdx.x * 4 + (threadIdx.x >> 6);
  const int task = wid >> 1;  // 16-row group
  if (task >= NN / 16) return;
  const int h = wid & 1;      // column half
  const int l = threadIdx.x & 63;
  const int lr = l & 15, lg = l >> 4;
  const int row = task * 16 + lr;
  const int c0 = h * 64;

  f32x4 acc[4];
  #pragma unroll
  for (int n = 0; n < 4; ++n) acc[n] = (f32x4){0.f, 0.f, 0.f, 0.f};

  #pragma unroll
  for (int kg = 0; kg < 4; ++kg) {
    int kb = kg * 32 + lg * 8;
    short8 a = *(const short8*)&hprev[(long)row * 128 + kb];
    #pragma unroll
    for (int n = 0; n < 4; ++n) {
      short8 b = *(const short8*)&Wlt[(c0 + n * 16 + lr) * 128 + kb];
      acc[n] = __builtin_amdgcn_mfma_f32_16x16x32_bf16(b, a, acc[n], 0, 0, 0);
    }
  }

  const int wb = lg * 4;
  #pragma unroll
  for (int n = 0; n < 4; ++n) {
    int c = c0 + n * 16 + wb;
    uint2 ag = *(const uint2*)(aggbf + ((long)row * TT + t) * 64 + (c >> 1));
    float4 bs = *(const float4*)&bsum[c];
    float o0 = tanhf(acc[n][0] + bf_lo(ag.x) + bs.x);
    float o1 = tanhf(acc[n][1] + bf_hi(ag.x) + bs.y);
    float o2 = tanhf(acc[n][2] + bf_lo(ag.y) + bs.z);
    float o3 = tanhf(acc[n][3] + bf_hi(ag.y) + bs.w);
    *(float4*)(out + ((long)row * TT + t) * 128 + c) = make_float4(o0, o1, o2, o3);
    unsigned u0 = (unsigned)f2bf(o0) | ((unsigned)f2bf(o1) << 16);
    unsigned u1 = (unsigned)f2bf(o2) | ((unsigned)f2bf(o3) << 16);
    *(uint2*)(hnew + (long)row * 64 + (c >> 1)) = make_uint2(u0, u1);
  }
}

extern "C" void kernel_launch(void* const* d_in, const int* in_sizes, int n_in,
                              void* d_out, int out_size, void* d_ws, size_t ws_size,
                              hipStream_t stream) {
  const float* x  = (const float*)d_in[0];
  const int*   ei = (const int*)d_in[1];
  const float* Wc = (const float*)d_in[2];
  const float* bc = (const float*)d_in[3];
  const float* Wl = (const float*)d_in[4];
  const float* bl = (const float*)d_in[5];
  float* out = (float*)d_out;
  const int E = in_sizes[1] / 2;
  const int* srcp = ei;
  const int* dstp = ei + E;

  char* w = (char*)d_ws;
  auto alloc = [&](size_t bytes) {
    char* p = w;
    w += (bytes + 255) & ~(size_t)255;
    return p;
  };
  int*            deg    = (int*)alloc(sizeof(int) * NN);
  float*          dinv   = (float*)alloc(sizeof(float) * NN);
  int*            rowptr = (int*)alloc(sizeof(int) * (NN + 1));
  int*            cur    = (int*)alloc(sizeof(int) * NN);
  int*            bsums  = (int*)alloc(sizeof(int) * (SCAN_NB + 1));
  int*            col    = (int*)alloc(sizeof(int) * (size_t)E);
  unsigned*       Yall   = (unsigned*)alloc(sizeof(unsigned) * (size_t)MT * 64);  // 204.8 MB
  unsigned*       aggbf  = (unsigned*)alloc(sizeof(unsigned) * (size_t)MT * 64);  // 204.8 MB
  unsigned*       hbf0   = (unsigned*)alloc(sizeof(unsigned) * (size_t)NN * 64);  // 12.8 MB
  unsigned*       hbf1   = (unsigned*)alloc(sizeof(unsigned) * (size_t)NN * 64);  // 12.8 MB
  float*          bsum   = (float*)alloc(sizeof(float) * DD);
  unsigned short* Wct    = (unsigned short*)alloc(sizeof(unsigned short) * 128 * 128);
  unsigned short* Wlt    = (unsigned short*)alloc(sizeof(unsigned short) * 128 * 128);

  k_init<<<(NN + 255) / 256, 256, 0, stream>>>(deg, cur);
  k_deg_count<<<(E + 255) / 256, 256, 0, stream>>>(dstp, deg, E);
  k_scan1<<<SCAN_NB, SCAN_B, 0, stream>>>(deg, rowptr, bsums, dinv);
  k_scan2<<<1, 64, 0, stream>>>(bsums);
  k_scan3<<<SCAN_NB, SCAN_B, 0, stream>>>(rowptr, bsums);
  k_fill<<<(E + 255) / 256, 256, 0, stream>>>(srcp, dstp, rowptr, cur, col, E);
  k_wprep<<<128, 128, 0, stream>>>(Wc, Wl, bc, bl, Wct, Wlt, bsum);

  // Y_all = bf16((x @ Wc) * dinv_src) for all N*T rows
  k_gemmx<<<MT / 128, 256, 0, stream>>>(x, Wct, dinv, Yall);
  // single-pass gather: block per node, 4KB coalesced row reads, step0 fused
  k_gatherN<<<NN, 256, 0, stream>>>((const u32x4*)Yall, col, rowptr, dinv, bsum,
                                    aggbf, out, hbf0);

  const int HB = ((NN / 16) * 2 + 3) / 4;  // 1563 blocks (4 waves each)
  for (int t = 1; t < TT; ++t) {
    unsigned* hprev = (t & 1) ? hbf0 : hbf1;
    unsigned* hnew  = (t & 1) ? hbf1 : hbf0;
    k_gemmh<<<HB, 256, 0, stream>>>((const unsigned short*)hprev, Wlt, aggbf, bsum,
                                    out, hnew, t);
  }
}

// Round 10
// 1744.323 us; speedup vs baseline: 1.1232x; 1.0508x over previous
//
#include <hip/hip_runtime.h>
#include <math.h>

#define NN 50000
#define TT 16
#define DD 128
#define MT (NN * TT)
#define SCAN_B 1024
#define SCAN_NB ((NN + SCAN_B - 1) / SCAN_B)  // 49

typedef __attribute__((ext_vector_type(8))) short short8;
typedef __attribute__((ext_vector_type(4))) float f32x4;
typedef __attribute__((ext_vector_type(4))) unsigned u32x4;

// ---------- bf16 helpers ----------
static __device__ __forceinline__ unsigned short f2bf(float f) {
  unsigned u = __float_as_uint(f);
  u += 0x7FFFu + ((u >> 16) & 1u);  // RNE
  return (unsigned short)(u >> 16);
}
static __device__ __forceinline__ float bf_lo(unsigned v) {
  return __uint_as_float(v << 16);
}
static __device__ __forceinline__ float bf_hi(unsigned v) {
  return __uint_as_float(v & 0xffff0000u);
}

// ---------- graph preprocessing ----------

__global__ void k_init(int* __restrict__ deg, int* __restrict__ cur) {
  int i = blockIdx.x * blockDim.x + threadIdx.x;
  if (i < NN) { deg[i] = 1; cur[i] = 0; }  // self loop; fill cursor
}

__global__ void k_deg_count(const int* __restrict__ dst, int* __restrict__ deg, int e) {
  int i = blockIdx.x * blockDim.x + threadIdx.x;
  if (i < e) atomicAdd(&deg[dst[i]], 1);
}

// scan over (deg-1) -> rowptr (block-local) + dinv fold
__global__ __launch_bounds__(SCAN_B) void k_scan1(const int* __restrict__ deg,
                                                  int* __restrict__ rowptr,
                                                  int* __restrict__ bsums,
                                                  float* __restrict__ dinv) {
  __shared__ int sm[SCAN_B];
  int tid = threadIdx.x;
  int i = blockIdx.x * SCAN_B + tid;
  int d = (i < NN) ? deg[i] : 1;
  if (i < NN) dinv[i] = rsqrtf((float)d);
  int v = d - 1;
  sm[tid] = v;
  __syncthreads();
  for (int off = 1; off < SCAN_B; off <<= 1) {
    int t = (tid >= off) ? sm[tid - off] : 0;
    __syncthreads();
    sm[tid] += t;
    __syncthreads();
  }
  if (i < NN) rowptr[i] = sm[tid] - v;
  if (tid == SCAN_B - 1) bsums[blockIdx.x] = sm[tid];
}

__global__ void k_scan2(int* __restrict__ bsums) {
  __shared__ int sm[64];
  int tid = threadIdx.x;
  int v = (tid < SCAN_NB) ? bsums[tid] : 0;
  sm[tid] = v;
  __syncthreads();
  for (int off = 1; off < 64; off <<= 1) {
    int t = (tid >= off) ? sm[tid - off] : 0;
    __syncthreads();
    sm[tid] += t;
    __syncthreads();
  }
  if (tid < SCAN_NB) bsums[tid] = sm[tid] - v;
  if (tid == 63) bsums[SCAN_NB] = sm[63];
}

__global__ __launch_bounds__(SCAN_B) void k_scan3(int* __restrict__ rowptr,
                                                  const int* __restrict__ bsums) {
  int i = blockIdx.x * SCAN_B + threadIdx.x;
  if (i < NN) rowptr[i] += bsums[blockIdx.x];
  if (i == 0) rowptr[NN] = bsums[SCAN_NB];
}

__global__ void k_fill(const int* __restrict__ src, const int* __restrict__ dst,
                       const int* __restrict__ rowptr, int* __restrict__ cur,
                       int* __restrict__ col, int e) {
  int i = blockIdx.x * blockDim.x + threadIdx.x;
  if (i < e) {
    int d = dst[i];
    int slot = atomicAdd(&cur[d], 1);
    col[rowptr[d] + slot] = src[i];
  }
}

// W^T bf16 + bsum fold: Wt[n*128+k] = bf16(W[k*128+n]); block = n, thread = k
__global__ void k_wprep(const float* __restrict__ Wc, const float* __restrict__ Wl,
                        const float* __restrict__ bc, const float* __restrict__ bl,
                        unsigned short* __restrict__ Wct, unsigned short* __restrict__ Wlt,
                        float* __restrict__ bsum) {
  int n = blockIdx.x, k = threadIdx.x;
  Wct[n * 128 + k] = f2bf(Wc[k * 128 + n]);
  Wlt[n * 128 + k] = f2bf(Wl[k * 128 + n]);
  if (n == 0) bsum[k] = bc[k] + bl[k];
}

// ---------- GEMM-X (MFMA bf16, swapped operands): Y[row] = bf16((X[row]@Wc)*dinv[row>>4]) ----------
__global__ __launch_bounds__(256) void k_gemmx(
    const float* __restrict__ X, const unsigned short* __restrict__ Wct,
    const float* __restrict__ dinv, unsigned* __restrict__ Yall)
{
  __shared__ unsigned short sA[128 * 136];  // sA[r][k], pad 136
  const int tid = threadIdx.x;
  const long row0 = (long)blockIdx.x * 128;

  // coalesced staging: wave reads 1KB contiguous per instruction
  {
    const float4* xp = (const float4*)(X + row0 * 128);
    #pragma unroll
    for (int it = 0; it < 16; ++it) {
      float4 v = xp[it * 256 + tid];
      int q = it * 256 + tid;          // float4 index in tile
      int r = q >> 5;                  // row
      int k = (q & 31) * 4;            // col
      unsigned u0 = (unsigned)f2bf(v.x) | ((unsigned)f2bf(v.y) << 16);
      unsigned u1 = (unsigned)f2bf(v.z) | ((unsigned)f2bf(v.w) << 16);
      *(uint2*)&sA[r * 136 + k] = make_uint2(u0, u1);
    }
  }
  __syncthreads();

  const int w = tid >> 6, l = tid & 63;
  const int lr = l & 15;
  const int lk = (l >> 4) << 3;
  f32x4 acc[2][8];
  #pragma unroll
  for (int i = 0; i < 2; ++i)
    #pragma unroll
    for (int n = 0; n < 8; ++n) acc[i][n] = (f32x4){0.f, 0.f, 0.f, 0.f};

  #pragma unroll
  for (int kg = 0; kg < 4; ++kg) {
    int kb = kg * 32 + lk;
    short8 a0 = *(const short8*)&sA[(w * 32 + lr) * 136 + kb];
    short8 a1 = *(const short8*)&sA[(w * 32 + 16 + lr) * 136 + kb];
    #pragma unroll
    for (int n = 0; n < 8; ++n) {
      short8 b = *(const short8*)&Wct[(n * 16 + lr) * 128 + kb];
      // swapped: lane holds xrow = l&15, wcol = (l>>4)*4+reg
      acc[0][n] = __builtin_amdgcn_mfma_f32_16x16x32_bf16(b, a0, acc[0][n], 0, 0, 0);
      acc[1][n] = __builtin_amdgcn_mfma_f32_16x16x32_bf16(b, a1, acc[1][n], 0, 0, 0);
    }
  }

  const int wb = (l >> 4) * 4;
  #pragma unroll
  for (int i = 0; i < 2; ++i) {
    long row = row0 + w * 32 + i * 16 + lr;
    float s = dinv[row >> 4];  // row = node*16+t
    #pragma unroll
    for (int n = 0; n < 8; ++n) {
      int c = n * 16 + wb;
      unsigned u0 = (unsigned)f2bf(acc[i][n][0] * s) | ((unsigned)f2bf(acc[i][n][1] * s) << 16);
      unsigned u1 = (unsigned)f2bf(acc[i][n][2] * s) | ((unsigned)f2bf(acc[i][n][3] * s) << 16);
      *(uint2*)(Yall + row * 64 + (c >> 1)) = make_uint2(u0, u1);
    }
  }
}

// ---------- gather: one block per node, all 16 t per edge (4KB coalesced row reads) ----------
// thread tid covers t = tid>>4, d = (tid&15)*8 .. +8  (one u32x4 = 8 bf16)
__global__ __launch_bounds__(256) void k_gatherN(
    const u32x4* __restrict__ Yall,  // [NN][256] u32x4
    const int* __restrict__ col, const int* __restrict__ rowptr,
    const float* __restrict__ dinv, unsigned* __restrict__ aggbf)
{
  const int n = blockIdx.x;
  const int tid = threadIdx.x;
  float a0, a1, a2, a3, a4, a5, a6, a7;
  {
    u32x4 v = Yall[(long)n * 256 + tid];  // self loop
    a0 = bf_lo(v.x); a1 = bf_hi(v.x); a2 = bf_lo(v.y); a3 = bf_hi(v.y);
    a4 = bf_lo(v.z); a5 = bf_hi(v.z); a6 = bf_lo(v.w); a7 = bf_hi(v.w);
  }
  int j = rowptr[n];
  const int end = rowptr[n + 1];
  for (; j + 4 <= end; j += 4) {
    u32x4 v0 = Yall[(long)col[j]     * 256 + tid];
    u32x4 v1 = Yall[(long)col[j + 1] * 256 + tid];
    u32x4 v2 = Yall[(long)col[j + 2] * 256 + tid];
    u32x4 v3 = Yall[(long)col[j + 3] * 256 + tid];
    a0 += bf_lo(v0.x); a1 += bf_hi(v0.x); a2 += bf_lo(v0.y); a3 += bf_hi(v0.y);
    a4 += bf_lo(v0.z); a5 += bf_hi(v0.z); a6 += bf_lo(v0.w); a7 += bf_hi(v0.w);
    a0 += bf_lo(v1.x); a1 += bf_hi(v1.x); a2 += bf_lo(v1.y); a3 += bf_hi(v1.y);
    a4 += bf_lo(v1.z); a5 += bf_hi(v1.z); a6 += bf_lo(v1.w); a7 += bf_hi(v1.w);
    a0 += bf_lo(v2.x); a1 += bf_hi(v2.x); a2 += bf_lo(v2.y); a3 += bf_hi(v2.y);
    a4 += bf_lo(v2.z); a5 += bf_hi(v2.z); a6 += bf_lo(v2.w); a7 += bf_hi(v2.w);
    a0 += bf_lo(v3.x); a1 += bf_hi(v3.x); a2 += bf_lo(v3.y); a3 += bf_hi(v3.y);
    a4 += bf_lo(v3.z); a5 += bf_hi(v3.z); a6 += bf_lo(v3.w); a7 += bf_hi(v3.w);
  }
  for (; j < end; ++j) {
    u32x4 v = Yall[(long)col[j] * 256 + tid];
    a0 += bf_lo(v.x); a1 += bf_hi(v.x); a2 += bf_lo(v.y); a3 += bf_hi(v.y);
    a4 += bf_lo(v.z); a5 += bf_hi(v.z); a6 += bf_lo(v.w); a7 += bf_hi(v.w);
  }
  const float di = dinv[n];
  u32x4 u;
  u.x = (unsigned)f2bf(di * a0) | ((unsigned)f2bf(di * a1) << 16);
  u.y = (unsigned)f2bf(di * a2) | ((unsigned)f2bf(di * a3) << 16);
  u.z = (unsigned)f2bf(di * a4) | ((unsigned)f2bf(di * a5) << 16);
  u.w = (unsigned)f2bf(di * a6) | ((unsigned)f2bf(di * a7) << 16);
  const int t = tid >> 4, dq = tid & 15;
  __builtin_nontemporal_store(u, (u32x4*)(aggbf + ((long)n * TT + t) * 64 + dq * 4));
}

// ---------- fused recurrence: ALL 16 timesteps in one launch ----------
// Per-node independence: h_t[n] depends only on h_{t-1}[n] + agg_t[n].
// Wave = 16 nodes; h tile lives in wave-private LDS [16][136] bf16
// (272B row stride -> 2-way bank conflicts = free). Per step:
// read h B-frags (LDS) -> 32 MFMA vs L1-hot Wlt -> tanh -> out + LDS h.
__global__ __launch_bounds__(256) void k_rnn(
    const unsigned* __restrict__ aggbf,      // [NN][TT][64] uint (2 bf16)
    const unsigned short* __restrict__ Wlt,  // [c][k] bf16 W_lin^T
    const float* __restrict__ bsum,
    float* __restrict__ out)
{
  __shared__ unsigned short hl[4][16][136];
  const int wv = threadIdx.x >> 6;
  const int l  = threadIdx.x & 63;
  const int task = blockIdx.x * 4 + wv;
  const bool act = task < (NN / 16);
  const int lr = l & 15, lg = l >> 4;
  const long row = (long)task * 16 + lr;

  float4 bsv[8];
  #pragma unroll
  for (int n = 0; n < 8; ++n) bsv[n] = *(const float4*)&bsum[n * 16 + lg * 4];

  // t = 0: h0 = tanh(agg0 + bsum)  (h_{-1} = 0, no MFMA)
  if (act) {
    #pragma unroll
    for (int n = 0; n < 8; ++n) {
      uint2 ag = *(const uint2*)(aggbf + (row * TT) * 64 + (n * 8 + lg * 2));
      float o0 = tanhf(bf_lo(ag.x) + bsv[n].x);
      float o1 = tanhf(bf_hi(ag.x) + bsv[n].y);
      float o2 = tanhf(bf_lo(ag.y) + bsv[n].z);
      float o3 = tanhf(bf_hi(ag.y) + bsv[n].w);
      *(float4*)(out + (row * TT) * 128 + n * 16 + lg * 4) = make_float4(o0, o1, o2, o3);
      unsigned u0 = (unsigned)f2bf(o0) | ((unsigned)f2bf(o1) << 16);
      unsigned u1 = (unsigned)f2bf(o2) | ((unsigned)f2bf(o3) << 16);
      *(uint2*)&hl[wv][lr][n * 16 + lg * 4] = make_uint2(u0, u1);
    }
  }
  __syncthreads();

  for (int t = 1; t < TT; ++t) {
    // B-fragments of h_{t-1}: lane(col=lr, kgrp=lg) reads 16B per kg
    short8 bfr[4];
    if (act) {
      #pragma unroll
      for (int kg = 0; kg < 4; ++kg)
        bfr[kg] = *(const short8*)&hl[wv][lr][kg * 32 + lg * 8];
    }
    __syncthreads();  // reads drained before h_t overwrites (WAR)
    if (act) {
      f32x4 acc[8];
      #pragma unroll
      for (int n = 0; n < 8; ++n) acc[n] = (f32x4){0.f, 0.f, 0.f, 0.f};
      #pragma unroll
      for (int kg = 0; kg < 4; ++kg) {
        const int kb = kg * 32 + lg * 8;
        #pragma unroll
        for (int n = 0; n < 8; ++n) {
          short8 b = *(const short8*)&Wlt[(n * 16 + lr) * 128 + kb];
          acc[n] = __builtin_amdgcn_mfma_f32_16x16x32_bf16(b, bfr[kg], acc[n], 0, 0, 0);
        }
      }
      #pragma unroll
      for (int n = 0; n < 8; ++n) {
        uint2 ag = *(const uint2*)(aggbf + (row * TT + t) * 64 + (n * 8 + lg * 2));
        float o0 = tanhf(acc[n][0] + bf_lo(ag.x) + bsv[n].x);
        float o1 = tanhf(acc[n][1] + bf_hi(ag.x) + bsv[n].y);
        float o2 = tanhf(acc[n][2] + bf_lo(ag.y) + bsv[n].z);
        float o3 = tanhf(acc[n][3] + bf_hi(ag.y) + bsv[n].w);
        *(float4*)(out + (row * TT + t) * 128 + n * 16 + lg * 4) = make_float4(o0, o1, o2, o3);
        unsigned u0 = (unsigned)f2bf(o0) | ((unsigned)f2bf(o1) << 16);
        unsigned u1 = (unsigned)f2bf(o2) | ((unsigned)f2bf(o3) << 16);
        *(uint2*)&hl[wv][lr][n * 16 + lg * 4] = make_uint2(u0, u1);
      }
    }
    __syncthreads();  // h_t visible before next step's reads
  }
}

extern "C" void kernel_launch(void* const* d_in, const int* in_sizes, int n_in,
                              void* d_out, int out_size, void* d_ws, size_t ws_size,
                              hipStream_t stream) {
  const float* x  = (const float*)d_in[0];
  const int*   ei = (const int*)d_in[1];
  const float* Wc = (const float*)d_in[2];
  const float* bc = (const float*)d_in[3];
  const float* Wl = (const float*)d_in[4];
  const float* bl = (const float*)d_in[5];
  float* out = (float*)d_out;
  const int E = in_sizes[1] / 2;
  const int* srcp = ei;
  const int* dstp = ei + E;

  char* w = (char*)d_ws;
  auto alloc = [&](size_t bytes) {
    char* p = w;
    w += (bytes + 255) & ~(size_t)255;
    return p;
  };
  int*            deg    = (int*)alloc(sizeof(int) * NN);
  float*          dinv   = (float*)alloc(sizeof(float) * NN);
  int*            rowptr = (int*)alloc(sizeof(int) * (NN + 1));
  int*            cur    = (int*)alloc(sizeof(int) * NN);
  int*            bsums  = (int*)alloc(sizeof(int) * (SCAN_NB + 1));
  int*            col    = (int*)alloc(sizeof(int) * (size_t)E);
  unsigned*       Yall   = (unsigned*)alloc(sizeof(unsigned) * (size_t)MT * 64);  // 204.8 MB
  unsigned*       aggbf  = (unsigned*)alloc(sizeof(unsigned) * (size_t)MT * 64);  // 204.8 MB
  float*          bsum   = (float*)alloc(sizeof(float) * DD);
  unsigned short* Wct    = (unsigned short*)alloc(sizeof(unsigned short) * 128 * 128);
  unsigned short* Wlt    = (unsigned short*)alloc(sizeof(unsigned short) * 128 * 128);

  k_init<<<(NN + 255) / 256, 256, 0, stream>>>(deg, cur);
  k_deg_count<<<(E + 255) / 256, 256, 0, stream>>>(dstp, deg, E);
  k_scan1<<<SCAN_NB, SCAN_B, 0, stream>>>(deg, rowptr, bsums, dinv);
  k_scan2<<<1, 64, 0, stream>>>(bsums);
  k_scan3<<<SCAN_NB, SCAN_B, 0, stream>>>(rowptr, bsums);
  k_fill<<<(E + 255) / 256, 256, 0, stream>>>(srcp, dstp, rowptr, cur, col, E);
  k_wprep<<<128, 128, 0, stream>>>(Wc, Wl, bc, bl, Wct, Wlt, bsum);

  // Y_all = bf16((x @ Wc) * dinv_src) for all N*T rows
  k_gemmx<<<MT / 128, 256, 0, stream>>>(x, Wct, dinv, Yall);
  // single-pass gather: block per node, 4KB coalesced row reads, all t
  k_gatherN<<<NN, 256, 0, stream>>>((const u32x4*)Yall, col, rowptr, dinv, aggbf);
  // fused recurrence: one launch for all 16 timesteps
  const int RB = (NN / 16 + 3) / 4;  // 782 blocks x 4 waves x 16 nodes
  k_rnn<<<RB, 256, 0, stream>>>(aggbf, Wlt, bsum, out);
}

// Round 11
// 1234.975 us; speedup vs baseline: 1.5865x; 1.4124x over previous
//
#include <hip/hip_runtime.h>
#include <math.h>

#define NN 50000
#define TT 16
#define DD 128
#define MT (NN * TT)
#define SCAN_B 1024
#define SCAN_NB ((NN + SCAN_B - 1) / SCAN_B)  // 49

typedef __attribute__((ext_vector_type(8))) short short8;
typedef __attribute__((ext_vector_type(4))) float f32x4;

// ---------- bf16 helpers ----------
static __device__ __forceinline__ unsigned short f2bf(float f) {
  unsigned u = __float_as_uint(f);
  u += 0x7FFFu + ((u >> 16) & 1u);  // RNE
  return (unsigned short)(u >> 16);
}
static __device__ __forceinline__ float bf_lo(unsigned v) {
  return __uint_as_float(v << 16);
}
static __device__ __forceinline__ float bf_hi(unsigned v) {
  return __uint_as_float(v & 0xffff0000u);
}

// ---------- graph preprocessing ----------

__global__ void k_init(int* __restrict__ deg, int* __restrict__ cur) {
  int i = blockIdx.x * blockDim.x + threadIdx.x;
  if (i < NN) { deg[i] = 1; cur[i] = 0; }  // self loop; fill cursor
}

__global__ void k_deg_count(const int* __restrict__ dst, int* __restrict__ deg, int e) {
  int i = blockIdx.x * blockDim.x + threadIdx.x;
  if (i < e) atomicAdd(&deg[dst[i]], 1);
}

// scan over (deg-1) -> rowptr (block-local) + dinv fold
__global__ __launch_bounds__(SCAN_B) void k_scan1(const int* __restrict__ deg,
                                                  int* __restrict__ rowptr,
                                                  int* __restrict__ bsums,
                                                  float* __restrict__ dinv) {
  __shared__ int sm[SCAN_B];
  int tid = threadIdx.x;
  int i = blockIdx.x * SCAN_B + tid;
  int d = (i < NN) ? deg[i] : 1;
  if (i < NN) dinv[i] = rsqrtf((float)d);
  int v = d - 1;
  sm[tid] = v;
  __syncthreads();
  for (int off = 1; off < SCAN_B; off <<= 1) {
    int t = (tid >= off) ? sm[tid - off] : 0;
    __syncthreads();
    sm[tid] += t;
    __syncthreads();
  }
  if (i < NN) rowptr[i] = sm[tid] - v;
  if (tid == SCAN_B - 1) bsums[blockIdx.x] = sm[tid];
}

__global__ void k_scan2(int* __restrict__ bsums) {
  __shared__ int sm[64];
  int tid = threadIdx.x;
  int v = (tid < SCAN_NB) ? bsums[tid] : 0;
  sm[tid] = v;
  __syncthreads();
  for (int off = 1; off < 64; off <<= 1) {
    int t = (tid >= off) ? sm[tid - off] : 0;
    __syncthreads();
    sm[tid] += t;
    __syncthreads();
  }
  if (tid < SCAN_NB) bsums[tid] = sm[tid] - v;
  if (tid == 63) bsums[SCAN_NB] = sm[63];
}

__global__ __launch_bounds__(SCAN_B) void k_scan3(int* __restrict__ rowptr,
                                                  const int* __restrict__ bsums) {
  int i = blockIdx.x * SCAN_B + threadIdx.x;
  if (i < NN) rowptr[i] += bsums[blockIdx.x];
  if (i == 0) rowptr[NN] = bsums[SCAN_NB];
}

__global__ void k_fill(const int* __restrict__ src, const int* __restrict__ dst,
                       const int* __restrict__ rowptr, int* __restrict__ cur,
                       int* __restrict__ col, int e) {
  int i = blockIdx.x * blockDim.x + threadIdx.x;
  if (i < e) {
    int d = dst[i];
    int slot = atomicAdd(&cur[d], 1);
    col[rowptr[d] + slot] = src[i];
  }
}

// W^T bf16 + bsum fold: Wt[n*128+k] = bf16(W[k*128+n]); block = n, thread = k
__global__ void k_wprep(const float* __restrict__ Wc, const float* __restrict__ Wl,
                        const float* __restrict__ bc, const float* __restrict__ bl,
                        unsigned short* __restrict__ Wct, unsigned short* __restrict__ Wlt,
                        float* __restrict__ bsum) {
  int n = blockIdx.x, k = threadIdx.x;
  Wct[n * 128 + k] = f2bf(Wc[k * 128 + n]);
  Wlt[n * 128 + k] = f2bf(Wl[k * 128 + n]);
  if (n == 0) bsum[k] = bc[k] + bl[k];
}

// ---------- GEMM-X (MFMA bf16) -> int8 per-node-scaled Y ----------
// q = rint(acc * 127/m_node) (dinv cancels); scale_n = m_node * dinv_n / 127.
// One node's 16 rows x 128 cols = one wave's acc[i] quadrant -> wave allreduce max.
__global__ __launch_bounds__(256) void k_gemmx(
    const float* __restrict__ X, const unsigned short* __restrict__ Wct,
    const float* __restrict__ dinv, char* __restrict__ Yq, float* __restrict__ scaleN)
{
  __shared__ unsigned short sA[128 * 136];  // sA[r][k], pad 136
  const int tid = threadIdx.x;
  const long row0 = (long)blockIdx.x * 128;

  // coalesced staging: wave reads 1KB contiguous per instruction
  {
    const float4* xp = (const float4*)(X + row0 * 128);
    #pragma unroll
    for (int it = 0; it < 16; ++it) {
      float4 v = xp[it * 256 + tid];
      int q = it * 256 + tid;
      int r = q >> 5;
      int k = (q & 31) * 4;
      unsigned u0 = (unsigned)f2bf(v.x) | ((unsigned)f2bf(v.y) << 16);
      unsigned u1 = (unsigned)f2bf(v.z) | ((unsigned)f2bf(v.w) << 16);
      *(uint2*)&sA[r * 136 + k] = make_uint2(u0, u1);
    }
  }
  __syncthreads();

  const int w = tid >> 6, l = tid & 63;
  const int lr = l & 15;
  const int lk = (l >> 4) << 3;
  f32x4 acc[2][8];
  #pragma unroll
  for (int i = 0; i < 2; ++i)
    #pragma unroll
    for (int n = 0; n < 8; ++n) acc[i][n] = (f32x4){0.f, 0.f, 0.f, 0.f};

  #pragma unroll
  for (int kg = 0; kg < 4; ++kg) {
    int kb = kg * 32 + lk;
    short8 a0 = *(const short8*)&sA[(w * 32 + lr) * 136 + kb];
    short8 a1 = *(const short8*)&sA[(w * 32 + 16 + lr) * 136 + kb];
    #pragma unroll
    for (int n = 0; n < 8; ++n) {
      short8 b = *(const short8*)&Wct[(n * 16 + lr) * 128 + kb];
      acc[0][n] = __builtin_amdgcn_mfma_f32_16x16x32_bf16(b, a0, acc[0][n], 0, 0, 0);
      acc[1][n] = __builtin_amdgcn_mfma_f32_16x16x32_bf16(b, a1, acc[1][n], 0, 0, 0);
    }
  }

  const int wb = (l >> 4) * 4;
  #pragma unroll
  for (int i = 0; i < 2; ++i) {
    const long rbase = row0 + w * 32 + i * 16;       // node tile base row
    const int node = (int)(rbase >> 4);
    const long row = rbase + lr;
    // per-node max |acc| over this wave's quadrant
    float m = 0.f;
    #pragma unroll
    for (int n = 0; n < 8; ++n)
      #pragma unroll
      for (int r = 0; r < 4; ++r) m = fmaxf(m, fabsf(acc[i][n][r]));
    #pragma unroll
    for (int mask = 1; mask < 64; mask <<= 1)
      m = fmaxf(m, __shfl_xor(m, mask, 64));
    const float f = (m > 0.f) ? 127.f / m : 0.f;
    if (l == 0) scaleN[node] = m * dinv[node] * (1.f / 127.f);
    #pragma unroll
    for (int n = 0; n < 8; ++n) {
      int q0 = (int)__builtin_rintf(acc[i][n][0] * f);
      int q1 = (int)__builtin_rintf(acc[i][n][1] * f);
      int q2 = (int)__builtin_rintf(acc[i][n][2] * f);
      int q3 = (int)__builtin_rintf(acc[i][n][3] * f);
      unsigned u = (unsigned)(q0 & 255) | ((unsigned)(q1 & 255) << 8) |
                   ((unsigned)(q2 & 255) << 16) | ((unsigned)(q3 & 255) << 24);
      *(unsigned*)(Yq + row * 128 + n * 16 + wb) = u;
    }
  }
}

// ---------- gather: one block per node, int8 rows (2KB coalesced) ----------
// thread tid: t = tid>>4, d = (tid&15)*8..+8  (one uint2 = 8 int8)
__global__ __launch_bounds__(256) void k_gatherN(
    const uint2* __restrict__ Yq,  // [NN][256] uint2 (8 int8 each)
    const float* __restrict__ scaleN,
    const int* __restrict__ col, const int* __restrict__ rowptr,
    const float* __restrict__ dinv, unsigned* __restrict__ aggbf)
{
  const int n = blockIdx.x;
  const int tid = threadIdx.x;
  float a0 = 0, a1 = 0, a2 = 0, a3 = 0, a4 = 0, a5 = 0, a6 = 0, a7 = 0;
  {
    uint2 v = Yq[(long)n * 256 + tid];  // self loop
    float ss = scaleN[n];
    a0 = fmaf((float)(signed char)(v.x),       ss, a0);
    a1 = fmaf((float)(signed char)(v.x >> 8),  ss, a1);
    a2 = fmaf((float)(signed char)(v.x >> 16), ss, a2);
    a3 = fmaf((float)(signed char)(v.x >> 24), ss, a3);
    a4 = fmaf((float)(signed char)(v.y),       ss, a4);
    a5 = fmaf((float)(signed char)(v.y >> 8),  ss, a5);
    a6 = fmaf((float)(signed char)(v.y >> 16), ss, a6);
    a7 = fmaf((float)(signed char)(v.y >> 24), ss, a7);
  }
  int j = rowptr[n];
  const int end = rowptr[n + 1];
  for (; j + 4 <= end; j += 4) {
    int s0 = col[j], s1 = col[j + 1], s2 = col[j + 2], s3 = col[j + 3];
    float c0 = scaleN[s0], c1 = scaleN[s1], c2 = scaleN[s2], c3 = scaleN[s3];
    uint2 v0 = Yq[(long)s0 * 256 + tid];
    uint2 v1 = Yq[(long)s1 * 256 + tid];
    uint2 v2 = Yq[(long)s2 * 256 + tid];
    uint2 v3 = Yq[(long)s3 * 256 + tid];
    a0 = fmaf((float)(signed char)(v0.x),       c0, a0);
    a1 = fmaf((float)(signed char)(v0.x >> 8),  c0, a1);
    a2 = fmaf((float)(signed char)(v0.x >> 16), c0, a2);
    a3 = fmaf((float)(signed char)(v0.x >> 24), c0, a3);
    a4 = fmaf((float)(signed char)(v0.y),       c0, a4);
    a5 = fmaf((float)(signed char)(v0.y >> 8),  c0, a5);
    a6 = fmaf((float)(signed char)(v0.y >> 16), c0, a6);
    a7 = fmaf((float)(signed char)(v0.y >> 24), c0, a7);
    a0 = fmaf((float)(signed char)(v1.x),       c1, a0);
    a1 = fmaf((float)(signed char)(v1.x >> 8),  c1, a1);
    a2 = fmaf((float)(signed char)(v1.x >> 16), c1, a2);
    a3 = fmaf((float)(signed char)(v1.x >> 24), c1, a3);
    a4 = fmaf((float)(signed char)(v1.y),       c1, a4);
    a5 = fmaf((float)(signed char)(v1.y >> 8),  c1, a5);
    a6 = fmaf((float)(signed char)(v1.y >> 16), c1, a6);
    a7 = fmaf((float)(signed char)(v1.y >> 24), c1, a7);
    a0 = fmaf((float)(signed char)(v2.x),       c2, a0);
    a1 = fmaf((float)(signed char)(v2.x >> 8),  c2, a1);
    a2 = fmaf((float)(signed char)(v2.x >> 16), c2, a2);
    a3 = fmaf((float)(signed char)(v2.x >> 24), c2, a3);
    a4 = fmaf((float)(signed char)(v2.y),       c2, a4);
    a5 = fmaf((float)(signed char)(v2.y >> 8),  c2, a5);
    a6 = fmaf((float)(signed char)(v2.y >> 16), c2, a6);
    a7 = fmaf((float)(signed char)(v2.y >> 24), c2, a7);
    a0 = fmaf((float)(signed char)(v3.x),       c3, a0);
    a1 = fmaf((float)(signed char)(v3.x >> 8),  c3, a1);
    a2 = fmaf((float)(signed char)(v3.x >> 16), c3, a2);
    a3 = fmaf((float)(signed char)(v3.x >> 24), c3, a3);
    a4 = fmaf((float)(signed char)(v3.y),       c3, a4);
    a5 = fmaf((float)(signed char)(v3.y >> 8),  c3, a5);
    a6 = fmaf((float)(signed char)(v3.y >> 16), c3, a6);
    a7 = fmaf((float)(signed char)(v3.y >> 24), c3, a7);
  }
  for (; j < end; ++j) {
    int s = col[j];
    float cs = scaleN[s];
    uint2 v = Yq[(long)s * 256 + tid];
    a0 = fmaf((float)(signed char)(v.x),       cs, a0);
    a1 = fmaf((float)(signed char)(v.x >> 8),  cs, a1);
    a2 = fmaf((float)(signed char)(v.x >> 16), cs, a2);
    a3 = fmaf((float)(signed char)(v.x >> 24), cs, a3);
    a4 = fmaf((float)(signed char)(v.y),       cs, a4);
    a5 = fmaf((float)(signed char)(v.y >> 8),  cs, a5);
    a6 = fmaf((float)(signed char)(v.y >> 16), cs, a6);
    a7 = fmaf((float)(signed char)(v.y >> 24), cs, a7);
  }
  const float di = dinv[n];
  uint2 u;
  u.x = (unsigned)f2bf(di * a0) | ((unsigned)f2bf(di * a1) << 16);
  u.y = (unsigned)f2bf(di * a2) | ((unsigned)f2bf(di * a3) << 16);
  uint2 w;
  w.x = (unsigned)f2bf(di * a4) | ((unsigned)f2bf(di * a5) << 16);
  w.y = (unsigned)f2bf(di * a6) | ((unsigned)f2bf(di * a7) << 16);
  const int t = tid >> 4, dq = tid & 15;
  unsigned* ap = aggbf + ((long)n * TT + t) * 64 + dq * 4;
  __builtin_nontemporal_store(u.x, ap);
  __builtin_nontemporal_store(u.y, ap + 1);
  __builtin_nontemporal_store(w.x, ap + 2);
  __builtin_nontemporal_store(w.y, ap + 3);
}

// ---------- fused recurrence: ALL 16 timesteps in one launch ----------
__global__ __launch_bounds__(256) void k_rnn(
    const unsigned* __restrict__ aggbf,      // [NN][TT][64] uint (2 bf16)
    const unsigned short* __restrict__ Wlt,  // [c][k] bf16 W_lin^T
    const float* __restrict__ bsum,
    float* __restrict__ out)
{
  __shared__ unsigned short hl[4][16][136];
  const int wv = threadIdx.x >> 6;
  const int l  = threadIdx.x & 63;
  const int task = blockIdx.x * 4 + wv;
  const bool act = task < (NN / 16);
  const int lr = l & 15, lg = l >> 4;
  const long row = (long)task * 16 + lr;

  float4 bsv[8];
  #pragma unroll
  for (int n = 0; n < 8; ++n) bsv[n] = *(const float4*)&bsum[n * 16 + lg * 4];

  // t = 0: h0 = tanh(agg0 + bsum)
  if (act) {
    #pragma unroll
    for (int n = 0; n < 8; ++n) {
      uint2 ag = *(const uint2*)(aggbf + (row * TT) * 64 + (n * 8 + lg * 2));
      float o0 = tanhf(bf_lo(ag.x) + bsv[n].x);
      float o1 = tanhf(bf_hi(ag.x) + bsv[n].y);
      float o2 = tanhf(bf_lo(ag.y) + bsv[n].z);
      float o3 = tanhf(bf_hi(ag.y) + bsv[n].w);
      *(float4*)(out + (row * TT) * 128 + n * 16 + lg * 4) = make_float4(o0, o1, o2, o3);
      unsigned u0 = (unsigned)f2bf(o0) | ((unsigned)f2bf(o1) << 16);
      unsigned u1 = (unsigned)f2bf(o2) | ((unsigned)f2bf(o3) << 16);
      *(uint2*)&hl[wv][lr][n * 16 + lg * 4] = make_uint2(u0, u1);
    }
  }
  __syncthreads();

  for (int t = 1; t < TT; ++t) {
    short8 bfr[4];
    if (act) {
      #pragma unroll
      for (int kg = 0; kg < 4; ++kg)
        bfr[kg] = *(const short8*)&hl[wv][lr][kg * 32 + lg * 8];
    }
    __syncthreads();  // WAR: reads drained before overwrite
    if (act) {
      f32x4 acc[8];
      #pragma unroll
      for (int n = 0; n < 8; ++n) acc[n] = (f32x4){0.f, 0.f, 0.f, 0.f};
      #pragma unroll
      for (int kg = 0; kg < 4; ++kg) {
        const int kb = kg * 32 + lg * 8;
        #pragma unroll
        for (int n = 0; n < 8; ++n) {
          short8 b = *(const short8*)&Wlt[(n * 16 + lr) * 128 + kb];
          acc[n] = __builtin_amdgcn_mfma_f32_16x16x32_bf16(b, bfr[kg], acc[n], 0, 0, 0);
        }
      }
      #pragma unroll
      for (int n = 0; n < 8; ++n) {
        uint2 ag = *(const uint2*)(aggbf + (row * TT + t) * 64 + (n * 8 + lg * 2));
        float o0 = tanhf(acc[n][0] + bf_lo(ag.x) + bsv[n].x);
        float o1 = tanhf(acc[n][1] + bf_hi(ag.x) + bsv[n].y);
        float o2 = tanhf(acc[n][2] + bf_lo(ag.y) + bsv[n].z);
        float o3 = tanhf(acc[n][3] + bf_hi(ag.y) + bsv[n].w);
        *(float4*)(out + (row * TT + t) * 128 + n * 16 + lg * 4) = make_float4(o0, o1, o2, o3);
        unsigned u0 = (unsigned)f2bf(o0) | ((unsigned)f2bf(o1) << 16);
        unsigned u1 = (unsigned)f2bf(o2) | ((unsigned)f2bf(o3) << 16);
        *(uint2*)&hl[wv][lr][n * 16 + lg * 4] = make_uint2(u0, u1);
      }
    }
    __syncthreads();
  }
}

extern "C" void kernel_launch(void* const* d_in, const int* in_sizes, int n_in,
                              void* d_out, int out_size, void* d_ws, size_t ws_size,
                              hipStream_t stream) {
  const float* x  = (const float*)d_in[0];
  const int*   ei = (const int*)d_in[1];
  const float* Wc = (const float*)d_in[2];
  const float* bc = (const float*)d_in[3];
  const float* Wl = (const float*)d_in[4];
  const float* bl = (const float*)d_in[5];
  float* out = (float*)d_out;
  const int E = in_sizes[1] / 2;
  const int* srcp = ei;
  const int* dstp = ei + E;

  char* w = (char*)d_ws;
  auto alloc = [&](size_t bytes) {
    char* p = w;
    w += (bytes + 255) & ~(size_t)255;
    return p;
  };
  int*            deg    = (int*)alloc(sizeof(int) * NN);
  float*          dinv   = (float*)alloc(sizeof(float) * NN);
  int*            rowptr = (int*)alloc(sizeof(int) * (NN + 1));
  int*            cur    = (int*)alloc(sizeof(int) * NN);
  int*            bsums  = (int*)alloc(sizeof(int) * (SCAN_NB + 1));
  int*            col    = (int*)alloc(sizeof(int) * (size_t)E);
  char*           Yq     = (char*)alloc((size_t)MT * DD);                         // 102.4 MB
  float*          scaleN = (float*)alloc(sizeof(float) * NN);
  unsigned*       aggbf  = (unsigned*)alloc(sizeof(unsigned) * (size_t)MT * 64);  // 204.8 MB
  float*          bsum   = (float*)alloc(sizeof(float) * DD);
  unsigned short* Wct    = (unsigned short*)alloc(sizeof(unsigned short) * 128 * 128);
  unsigned short* Wlt    = (unsigned short*)alloc(sizeof(unsigned short) * 128 * 128);

  k_init<<<(NN + 255) / 256, 256, 0, stream>>>(deg, cur);
  k_deg_count<<<(E + 255) / 256, 256, 0, stream>>>(dstp, deg, E);
  k_scan1<<<SCAN_NB, SCAN_B, 0, stream>>>(deg, rowptr, bsums, dinv);
  k_scan2<<<1, 64, 0, stream>>>(bsums);
  k_scan3<<<SCAN_NB, SCAN_B, 0, stream>>>(rowptr, bsums);
  k_fill<<<(E + 255) / 256, 256, 0, stream>>>(srcp, dstp, rowptr, cur, col, E);
  k_wprep<<<128, 128, 0, stream>>>(Wc, Wl, bc, bl, Wct, Wlt, bsum);

  // Yq = int8((x @ Wc) scaled per node; dinv folded into scaleN)
  k_gemmx<<<MT / 128, 256, 0, stream>>>(x, Wct, dinv, Yq, scaleN);
  // single-pass gather: block per node, 2KB coalesced int8 row reads
  k_gatherN<<<NN, 256, 0, stream>>>((const uint2*)Yq, scaleN, col, rowptr, dinv, aggbf);
  // fused recurrence: one launch for all 16 timesteps
  const int RB = (NN / 16 + 3) / 4;
  k_rnn<<<RB, 256, 0, stream>>>(aggbf, Wlt, bsum, out);
}

// Round 12
// 1053.696 us; speedup vs baseline: 1.8594x; 1.1720x over previous
//
#include <hip/hip_runtime.h>
#include <math.h>

#define NN 50000
#define TT 16
#define DD 128
#define MT (NN * TT)
#define SCAN_B 1024
#define SCAN_NB ((NN + SCAN_B - 1) / SCAN_B)  // 49

typedef __attribute__((ext_vector_type(8))) short short8;
typedef __attribute__((ext_vector_type(4))) float f32x4;

// ---------- bf16 helpers ----------
static __device__ __forceinline__ unsigned short f2bf(float f) {
  unsigned u = __float_as_uint(f);
  u += 0x7FFFu + ((u >> 16) & 1u);  // RNE
  return (unsigned short)(u >> 16);
}
static __device__ __forceinline__ float bf_lo(unsigned v) {
  return __uint_as_float(v << 16);
}
static __device__ __forceinline__ float bf_hi(unsigned v) {
  return __uint_as_float(v & 0xffff0000u);
}

// ---------- graph preprocessing ----------

__global__ void k_init(int* __restrict__ deg, int* __restrict__ cur) {
  int i = blockIdx.x * blockDim.x + threadIdx.x;
  if (i < NN) { deg[i] = 1; cur[i] = 0; }  // self loop; fill cursor
}

__global__ void k_deg_count(const int* __restrict__ dst, int* __restrict__ deg, int e) {
  int i = blockIdx.x * blockDim.x + threadIdx.x;
  if (i < e) atomicAdd(&deg[dst[i]], 1);
}

// scan over (deg-1) -> rowptr (block-local) + dinv fold
__global__ __launch_bounds__(SCAN_B) void k_scan1(const int* __restrict__ deg,
                                                  int* __restrict__ rowptr,
                                                  int* __restrict__ bsums,
                                                  float* __restrict__ dinv) {
  __shared__ int sm[SCAN_B];
  int tid = threadIdx.x;
  int i = blockIdx.x * SCAN_B + tid;
  int d = (i < NN) ? deg[i] : 1;
  if (i < NN) dinv[i] = rsqrtf((float)d);
  int v = d - 1;
  sm[tid] = v;
  __syncthreads();
  for (int off = 1; off < SCAN_B; off <<= 1) {
    int t = (tid >= off) ? sm[tid - off] : 0;
    __syncthreads();
    sm[tid] += t;
    __syncthreads();
  }
  if (i < NN) rowptr[i] = sm[tid] - v;
  if (tid == SCAN_B - 1) bsums[blockIdx.x] = sm[tid];
}

__global__ void k_scan2(int* __restrict__ bsums) {
  __shared__ int sm[64];
  int tid = threadIdx.x;
  int v = (tid < SCAN_NB) ? bsums[tid] : 0;
  sm[tid] = v;
  __syncthreads();
  for (int off = 1; off < 64; off <<= 1) {
    int t = (tid >= off) ? sm[tid - off] : 0;
    __syncthreads();
    sm[tid] += t;
    __syncthreads();
  }
  if (tid < SCAN_NB) bsums[tid] = sm[tid] - v;
  if (tid == 63) bsums[SCAN_NB] = sm[63];
}

__global__ __launch_bounds__(SCAN_B) void k_scan3(int* __restrict__ rowptr,
                                                  const int* __restrict__ bsums) {
  int i = blockIdx.x * SCAN_B + threadIdx.x;
  if (i < NN) rowptr[i] += bsums[blockIdx.x];
  if (i == 0) rowptr[NN] = bsums[SCAN_NB];
}

__global__ void k_fill(const int* __restrict__ src, const int* __restrict__ dst,
                       const int* __restrict__ rowptr, int* __restrict__ cur,
                       int* __restrict__ col, int e) {
  int i = blockIdx.x * blockDim.x + threadIdx.x;
  if (i < e) {
    int d = dst[i];
    int slot = atomicAdd(&cur[d], 1);
    col[rowptr[d] + slot] = src[i];
  }
}

// W^T bf16 + bsum fold: Wt[n*128+k] = bf16(W[k*128+n]); block = n, thread = k
__global__ void k_wprep(const float* __restrict__ Wc, const float* __restrict__ Wl,
                        const float* __restrict__ bc, const float* __restrict__ bl,
                        unsigned short* __restrict__ Wct, unsigned short* __restrict__ Wlt,
                        float* __restrict__ bsum) {
  int n = blockIdx.x, k = threadIdx.x;
  Wct[n * 128 + k] = f2bf(Wc[k * 128 + n]);
  Wlt[n * 128 + k] = f2bf(Wl[k * 128 + n]);
  if (n == 0) bsum[k] = bc[k] + bl[k];
}

// ---------- GEMM-X (MFMA bf16) -> int8 per-node-scaled Y ----------
// q = rint(acc * 127/m_node) (dinv cancels); scale_n = m_node * dinv_n / 127.
__global__ __launch_bounds__(256) void k_gemmx(
    const float* __restrict__ X, const unsigned short* __restrict__ Wct,
    const float* __restrict__ dinv, char* __restrict__ Yq, float* __restrict__ scaleN)
{
  __shared__ unsigned short sA[128 * 136];  // sA[r][k], pad 136
  const int tid = threadIdx.x;
  const long row0 = (long)blockIdx.x * 128;

  {
    const float4* xp = (const float4*)(X + row0 * 128);
    #pragma unroll
    for (int it = 0; it < 16; ++it) {
      float4 v = xp[it * 256 + tid];
      int q = it * 256 + tid;
      int r = q >> 5;
      int k = (q & 31) * 4;
      unsigned u0 = (unsigned)f2bf(v.x) | ((unsigned)f2bf(v.y) << 16);
      unsigned u1 = (unsigned)f2bf(v.z) | ((unsigned)f2bf(v.w) << 16);
      *(uint2*)&sA[r * 136 + k] = make_uint2(u0, u1);
    }
  }
  __syncthreads();

  const int w = tid >> 6, l = tid & 63;
  const int lr = l & 15;
  const int lk = (l >> 4) << 3;
  f32x4 acc[2][8];
  #pragma unroll
  for (int i = 0; i < 2; ++i)
    #pragma unroll
    for (int n = 0; n < 8; ++n) acc[i][n] = (f32x4){0.f, 0.f, 0.f, 0.f};

  #pragma unroll
  for (int kg = 0; kg < 4; ++kg) {
    int kb = kg * 32 + lk;
    short8 a0 = *(const short8*)&sA[(w * 32 + lr) * 136 + kb];
    short8 a1 = *(const short8*)&sA[(w * 32 + 16 + lr) * 136 + kb];
    #pragma unroll
    for (int n = 0; n < 8; ++n) {
      short8 b = *(const short8*)&Wct[(n * 16 + lr) * 128 + kb];
      acc[0][n] = __builtin_amdgcn_mfma_f32_16x16x32_bf16(b, a0, acc[0][n], 0, 0, 0);
      acc[1][n] = __builtin_amdgcn_mfma_f32_16x16x32_bf16(b, a1, acc[1][n], 0, 0, 0);
    }
  }

  const int wb = (l >> 4) * 4;
  #pragma unroll
  for (int i = 0; i < 2; ++i) {
    const long rbase = row0 + w * 32 + i * 16;
    const int node = (int)(rbase >> 4);
    const long row = rbase + lr;
    float m = 0.f;
    #pragma unroll
    for (int n = 0; n < 8; ++n)
      #pragma unroll
      for (int r = 0; r < 4; ++r) m = fmaxf(m, fabsf(acc[i][n][r]));
    #pragma unroll
    for (int mask = 1; mask < 64; mask <<= 1)
      m = fmaxf(m, __shfl_xor(m, mask, 64));
    const float f = (m > 0.f) ? 127.f / m : 0.f;
    if (l == 0) scaleN[node] = m * dinv[node] * (1.f / 127.f);
    #pragma unroll
    for (int n = 0; n < 8; ++n) {
      int q0 = (int)__builtin_rintf(acc[i][n][0] * f);
      int q1 = (int)__builtin_rintf(acc[i][n][1] * f);
      int q2 = (int)__builtin_rintf(acc[i][n][2] * f);
      int q3 = (int)__builtin_rintf(acc[i][n][3] * f);
      unsigned u = (unsigned)(q0 & 255) | ((unsigned)(q1 & 255) << 8) |
                   ((unsigned)(q2 & 255) << 16) | ((unsigned)(q3 & 255) << 24);
      *(unsigned*)(Yq + row * 128 + n * 16 + wb) = u;
    }
  }
}

// ---------- gather: one block per node, int8 rows (2KB coalesced) ----------
// aggT is t-major: [TT][NN][64] u32. thread tid: t = tid>>4, d = (tid&15)*8..+8
__global__ __launch_bounds__(256) void k_gatherN(
    const uint2* __restrict__ Yq,  // [NN][256] uint2 (8 int8 each)
    const float* __restrict__ scaleN,
    const int* __restrict__ col, const int* __restrict__ rowptr,
    const float* __restrict__ dinv, unsigned* __restrict__ aggT)
{
  const int n = blockIdx.x;
  const int tid = threadIdx.x;
  float a0 = 0, a1 = 0, a2 = 0, a3 = 0, a4 = 0, a5 = 0, a6 = 0, a7 = 0;
  {
    uint2 v = Yq[(long)n * 256 + tid];  // self loop
    float ss = scaleN[n];
    a0 = fmaf((float)(signed char)(v.x),       ss, a0);
    a1 = fmaf((float)(signed char)(v.x >> 8),  ss, a1);
    a2 = fmaf((float)(signed char)(v.x >> 16), ss, a2);
    a3 = fmaf((float)(signed char)(v.x >> 24), ss, a3);
    a4 = fmaf((float)(signed char)(v.y),       ss, a4);
    a5 = fmaf((float)(signed char)(v.y >> 8),  ss, a5);
    a6 = fmaf((float)(signed char)(v.y >> 16), ss, a6);
    a7 = fmaf((float)(signed char)(v.y >> 24), ss, a7);
  }
  int j = rowptr[n];
  const int end = rowptr[n + 1];
  for (; j + 4 <= end; j += 4) {
    int s0 = col[j], s1 = col[j + 1], s2 = col[j + 2], s3 = col[j + 3];
    float c0 = scaleN[s0], c1 = scaleN[s1], c2 = scaleN[s2], c3 = scaleN[s3];
    uint2 v0 = Yq[(long)s0 * 256 + tid];
    uint2 v1 = Yq[(long)s1 * 256 + tid];
    uint2 v2 = Yq[(long)s2 * 256 + tid];
    uint2 v3 = Yq[(long)s3 * 256 + tid];
    a0 = fmaf((float)(signed char)(v0.x),       c0, a0);
    a1 = fmaf((float)(signed char)(v0.x >> 8),  c0, a1);
    a2 = fmaf((float)(signed char)(v0.x >> 16), c0, a2);
    a3 = fmaf((float)(signed char)(v0.x >> 24), c0, a3);
    a4 = fmaf((float)(signed char)(v0.y),       c0, a4);
    a5 = fmaf((float)(signed char)(v0.y >> 8),  c0, a5);
    a6 = fmaf((float)(signed char)(v0.y >> 16), c0, a6);
    a7 = fmaf((float)(signed char)(v0.y >> 24), c0, a7);
    a0 = fmaf((float)(signed char)(v1.x),       c1, a0);
    a1 = fmaf((float)(signed char)(v1.x >> 8),  c1, a1);
    a2 = fmaf((float)(signed char)(v1.x >> 16), c1, a2);
    a3 = fmaf((float)(signed char)(v1.x >> 24), c1, a3);
    a4 = fmaf((float)(signed char)(v1.y),       c1, a4);
    a5 = fmaf((float)(signed char)(v1.y >> 8),  c1, a5);
    a6 = fmaf((float)(signed char)(v1.y >> 16), c1, a6);
    a7 = fmaf((float)(signed char)(v1.y >> 24), c1, a7);
    a0 = fmaf((float)(signed char)(v2.x),       c2, a0);
    a1 = fmaf((float)(signed char)(v2.x >> 8),  c2, a1);
    a2 = fmaf((float)(signed char)(v2.x >> 16), c2, a2);
    a3 = fmaf((float)(signed char)(v2.x >> 24), c2, a3);
    a4 = fmaf((float)(signed char)(v2.y),       c2, a4);
    a5 = fmaf((float)(signed char)(v2.y >> 8),  c2, a5);
    a6 = fmaf((float)(signed char)(v2.y >> 16), c2, a6);
    a7 = fmaf((float)(signed char)(v2.y >> 24), c2, a7);
    a0 = fmaf((float)(signed char)(v3.x),       c3, a0);
    a1 = fmaf((float)(signed char)(v3.x >> 8),  c3, a1);
    a2 = fmaf((float)(signed char)(v3.x >> 16), c3, a2);
    a3 = fmaf((float)(signed char)(v3.x >> 24), c3, a3);
    a4 = fmaf((float)(signed char)(v3.y),       c3, a4);
    a5 = fmaf((float)(signed char)(v3.y >> 8),  c3, a5);
    a6 = fmaf((float)(signed char)(v3.y >> 16), c3, a6);
    a7 = fmaf((float)(signed char)(v3.y >> 24), c3, a7);
  }
  for (; j < end; ++j) {
    int s = col[j];
    float cs = scaleN[s];
    uint2 v = Yq[(long)s * 256 + tid];
    a0 = fmaf((float)(signed char)(v.x),       cs, a0);
    a1 = fmaf((float)(signed char)(v.x >> 8),  cs, a1);
    a2 = fmaf((float)(signed char)(v.x >> 16), cs, a2);
    a3 = fmaf((float)(signed char)(v.x >> 24), cs, a3);
    a4 = fmaf((float)(signed char)(v.y),       cs, a4);
    a5 = fmaf((float)(signed char)(v.y >> 8),  cs, a5);
    a6 = fmaf((float)(signed char)(v.y >> 16), cs, a6);
    a7 = fmaf((float)(signed char)(v.y >> 24), cs, a7);
  }
  const float di = dinv[n];
  unsigned u0 = (unsigned)f2bf(di * a0) | ((unsigned)f2bf(di * a1) << 16);
  unsigned u1 = (unsigned)f2bf(di * a2) | ((unsigned)f2bf(di * a3) << 16);
  unsigned u2 = (unsigned)f2bf(di * a4) | ((unsigned)f2bf(di * a5) << 16);
  unsigned u3 = (unsigned)f2bf(di * a6) | ((unsigned)f2bf(di * a7) << 16);
  const int t = tid >> 4, dq = tid & 15;
  unsigned* ap = aggT + ((long)t * NN + n) * 64 + dq * 4;  // t-major
  __builtin_nontemporal_store(u0, ap);
  __builtin_nontemporal_store(u1, ap + 1);
  __builtin_nontemporal_store(u2, ap + 2);
  __builtin_nontemporal_store(u3, ap + 3);
}

// ---------- fused recurrence: all 16 t, 1 wave per 16 nodes ----------
// aggT t-major -> per step one contiguous 4KB tile, staged via LDS.
__global__ __launch_bounds__(64) void k_rnn(
    const unsigned* __restrict__ aggT,       // [TT][NN][64] u32 (2 bf16)
    const unsigned short* __restrict__ Wlt,  // [c][k] bf16 W_lin^T
    const float* __restrict__ bsum,
    float* __restrict__ out)
{
  __shared__ unsigned sag[16 * 72];        // agg tile, row pad 72 u32
  __shared__ unsigned short hl[16 * 144];  // h tile bf16, row pad 144 u16
  const int l = threadIdx.x;
  const int lr = l & 15, lg = l >> 4;
  const long nbase = (long)blockIdx.x * 16;
  const long row = nbase + lr;

  float4 bsv[8];
  #pragma unroll
  for (int n = 0; n < 8; ++n) bsv[n] = *(const float4*)&bsum[n * 16 + lg * 4];

  uint4 g[4];
  // stage agg[t=0] (contiguous 4KB -> LDS)
  {
    const uint4* src = (const uint4*)(aggT + nbase * 64);
    #pragma unroll
    for (int i = 0; i < 4; ++i) g[i] = src[i * 64 + l];
    #pragma unroll
    for (int i = 0; i < 4; ++i) {
      int gi = (i * 64 + l) * 4;  // u32 index in [16][64]
      *(uint4*)&sag[(gi >> 6) * 72 + (gi & 63)] = g[i];
    }
  }
  // prefetch t=1
  {
    const uint4* src = (const uint4*)(aggT + ((long)NN + nbase) * 64);
    #pragma unroll
    for (int i = 0; i < 4; ++i) g[i] = src[i * 64 + l];
  }
  __syncthreads();
  // t=0: h0 = tanh(agg0 + bsum)
  #pragma unroll
  for (int n = 0; n < 8; ++n) {
    uint2 ag = *(const uint2*)&sag[lr * 72 + n * 8 + lg * 2];
    float o0 = tanhf(bf_lo(ag.x) + bsv[n].x);
    float o1 = tanhf(bf_hi(ag.x) + bsv[n].y);
    float o2 = tanhf(bf_lo(ag.y) + bsv[n].z);
    float o3 = tanhf(bf_hi(ag.y) + bsv[n].w);
    *(float4*)(out + (row * TT) * 128 + n * 16 + lg * 4) = make_float4(o0, o1, o2, o3);
    unsigned u0 = (unsigned)f2bf(o0) | ((unsigned)f2bf(o1) << 16);
    unsigned u1 = (unsigned)f2bf(o2) | ((unsigned)f2bf(o3) << 16);
    *(uint2*)&hl[lr * 144 + n * 16 + lg * 4] = make_uint2(u0, u1);
  }
  __syncthreads();

  for (int t = 1; t < TT; ++t) {
    // write staged agg[t] (prev iteration's sag reads already drained: 1 wave, in-order DS)
    #pragma unroll
    for (int i = 0; i < 4; ++i) {
      int gi = (i * 64 + l) * 4;
      *(uint4*)&sag[(gi >> 6) * 72 + (gi & 63)] = g[i];
    }
    // prefetch t+1 (held in registers until next iteration's sag write)
    if (t + 1 < TT) {
      const uint4* src = (const uint4*)(aggT + ((long)(t + 1) * NN + nbase) * 64);
      #pragma unroll
      for (int i = 0; i < 4; ++i) g[i] = src[i * 64 + l];
    }
    // B-fragments of h_{t-1}
    short8 bfr[4];
    #pragma unroll
    for (int kg = 0; kg < 4; ++kg)
      bfr[kg] = *(const short8*)&hl[lr * 144 + kg * 32 + lg * 8];
    __syncthreads();  // 1-wave: ~free; orders sag/hl hazards conservatively

    f32x4 acc[8];
    #pragma unroll
    for (int n = 0; n < 8; ++n) acc[n] = (f32x4){0.f, 0.f, 0.f, 0.f};
    #pragma unroll
    for (int kg = 0; kg < 4; ++kg) {
      const int kb = kg * 32 + lg * 8;
      #pragma unroll
      for (int n = 0; n < 8; ++n) {
        short8 b = *(const short8*)&Wlt[(n * 16 + lr) * 128 + kb];
        acc[n] = __builtin_amdgcn_mfma_f32_16x16x32_bf16(b, bfr[kg], acc[n], 0, 0, 0);
      }
    }
    #pragma unroll
    for (int n = 0; n < 8; ++n) {
      uint2 ag = *(const uint2*)&sag[lr * 72 + n * 8 + lg * 2];
      float o0 = tanhf(acc[n][0] + bf_lo(ag.x) + bsv[n].x);
      float o1 = tanhf(acc[n][1] + bf_hi(ag.x) + bsv[n].y);
      float o2 = tanhf(acc[n][2] + bf_lo(ag.y) + bsv[n].z);
      float o3 = tanhf(acc[n][3] + bf_hi(ag.y) + bsv[n].w);
      *(float4*)(out + (row * TT + t) * 128 + n * 16 + lg * 4) = make_float4(o0, o1, o2, o3);
      unsigned u0 = (unsigned)f2bf(o0) | ((unsigned)f2bf(o1) << 16);
      unsigned u1 = (unsigned)f2bf(o2) | ((unsigned)f2bf(o3) << 16);
      *(uint2*)&hl[lr * 144 + n * 16 + lg * 4] = make_uint2(u0, u1);
    }
    __syncthreads();
  }
}

extern "C" void kernel_launch(void* const* d_in, const int* in_sizes, int n_in,
                              void* d_out, int out_size, void* d_ws, size_t ws_size,
                              hipStream_t stream) {
  const float* x  = (const float*)d_in[0];
  const int*   ei = (const int*)d_in[1];
  const float* Wc = (const float*)d_in[2];
  const float* bc = (const float*)d_in[3];
  const float* Wl = (const float*)d_in[4];
  const float* bl = (const float*)d_in[5];
  float* out = (float*)d_out;
  const int E = in_sizes[1] / 2;
  const int* srcp = ei;
  const int* dstp = ei + E;

  char* w = (char*)d_ws;
  auto alloc = [&](size_t bytes) {
    char* p = w;
    w += (bytes + 255) & ~(size_t)255;
    return p;
  };
  int*            deg    = (int*)alloc(sizeof(int) * NN);
  float*          dinv   = (float*)alloc(sizeof(float) * NN);
  int*            rowptr = (int*)alloc(sizeof(int) * (NN + 1));
  int*            cur    = (int*)alloc(sizeof(int) * NN);
  int*            bsums  = (int*)alloc(sizeof(int) * (SCAN_NB + 1));
  int*            col    = (int*)alloc(sizeof(int) * (size_t)E);
  char*           Yq     = (char*)alloc((size_t)MT * DD);                         // 102.4 MB
  float*          scaleN = (float*)alloc(sizeof(float) * NN);
  unsigned*       aggT   = (unsigned*)alloc(sizeof(unsigned) * (size_t)MT * 64);  // 204.8 MB
  float*          bsum   = (float*)alloc(sizeof(float) * DD);
  unsigned short* Wct    = (unsigned short*)alloc(sizeof(unsigned short) * 128 * 128);
  unsigned short* Wlt    = (unsigned short*)alloc(sizeof(unsigned short) * 128 * 128);

  k_init<<<(NN + 255) / 256, 256, 0, stream>>>(deg, cur);
  k_deg_count<<<(E + 255) / 256, 256, 0, stream>>>(dstp, deg, E);
  k_scan1<<<SCAN_NB, SCAN_B, 0, stream>>>(deg, rowptr, bsums, dinv);
  k_scan2<<<1, 64, 0, stream>>>(bsums);
  k_scan3<<<SCAN_NB, SCAN_B, 0, stream>>>(rowptr, bsums);
  k_fill<<<(E + 255) / 256, 256, 0, stream>>>(srcp, dstp, rowptr, cur, col, E);
  k_wprep<<<128, 128, 0, stream>>>(Wc, Wl, bc, bl, Wct, Wlt, bsum);

  // Yq = int8((x @ Wc) scaled per node; dinv folded into scaleN)
  k_gemmx<<<MT / 128, 256, 0, stream>>>(x, Wct, dinv, Yq, scaleN);
  // single-pass gather: block per node, 2KB coalesced int8 row reads; t-major agg out
  k_gatherN<<<NN, 256, 0, stream>>>((const uint2*)Yq, scaleN, col, rowptr, dinv, aggT);
  // fused recurrence: 1 wave per 16 nodes, agg staged via LDS (contiguous 4KB/step)
  k_rnn<<<NN / 16, 64, 0, stream>>>(aggT, Wlt, bsum, out);
}